// Round 3
// baseline (11604.953 us; speedup 1.0000x reference)
//
#include <hip/hip_runtime.h>
#include <math.h>

#define N_PTS 8192
#define M_PTS 2048
#define KLAST 10
#define VARS 3
#define OUTD 32
#define D1 80
#define D2 80
#define TP 68      // T pitch (floats)
#define WP 84      // W1T/W2T pitch
#define PB 4       // points per agg block

typedef float f4 __attribute__((ext_vector_type(4)));

__device__ __forceinline__ float gelu_f(float x) {
    return 0.5f * x * (1.0f + erff(x * 0.70710678118654752f));
}

// stage weights (transposed into LDS) + biases; caller barriers after.
__device__ __forceinline__ void stage_weights(
    float* W0T, float* W1T, float* W2T, float* bs,
    const float* __restrict__ W0g, const float* __restrict__ b0g,
    const float* __restrict__ W1g, const float* __restrict__ b1g,
    const float* __restrict__ W2g, const float* __restrict__ b2g, int t)
{
    for (int idx = t; idx < 36 * D1; idx += 256) {
        int k = idx / D1, col = idx - k * D1;
        W0T[col * 36 + k] = W0g[idx];                    // coalesced read
    }
    for (int idx = t; idx < D1 * D2; idx += 256) {
        int k = idx / D2, col = idx - k * D2;
        W1T[col * WP + k] = W1g[idx];
    }
    for (int idx = t; idx < D2 * OUTD; idx += 256) {
        int k = idx / OUTD, col = idx - k * OUTD;
        W2T[col * WP + k] = W2g[idx];
    }
    for (int idx = t; idx < 192; idx += 256)
        bs[idx] = (idx < 80) ? b0g[idx] : (idx < 160 ? b1g[idx - 80] : b2g[idx - 160]);
}

// 64-row tile MLP. On entry T rows 0..35 hold transposed activations (pitch TP).
// On exit T holds out[64][33]. Weights pre-staged. Barriers inside.
__device__ __forceinline__ void mlp_tile(
    float* T, const float* W0T, const float* W1T, const float* W2T,
    const float* bs, int t)
{
    const int tc = t & 15, tr = t >> 4;
    __syncthreads();                                     // staging of T done

    float acc1[5][4];
#pragma unroll
    for (int c = 0; c < 5; ++c) {
        float b = bs[tc + 16 * c];
#pragma unroll
        for (int r = 0; r < 4; ++r) acc1[c][r] = b;
    }
#pragma unroll
    for (int kk = 0; kk < 9; ++kk) {
        f4 a[4];
#pragma unroll
        for (int q = 0; q < 4; ++q) a[q] = *(const f4*)&T[(4 * kk + q) * TP + 4 * tr];
#pragma unroll
        for (int c = 0; c < 5; ++c) {
            f4 w = *(const f4*)&W0T[(tc + 16 * c) * 36 + 4 * kk];
#pragma unroll
            for (int q = 0; q < 4; ++q)
#pragma unroll
                for (int r = 0; r < 4; ++r) acc1[c][r] += a[q][r] * w[q];
        }
    }
    __syncthreads();
#pragma unroll
    for (int c = 0; c < 5; ++c) {
        f4 h;
#pragma unroll
        for (int r = 0; r < 4; ++r) h[r] = gelu_f(acc1[c][r]);
        *(f4*)&T[(tc + 16 * c) * TP + 4 * tr] = h;       // H1T
    }
    __syncthreads();

    float acc2[5][4];
#pragma unroll
    for (int c = 0; c < 5; ++c) {
        float b = bs[80 + tc + 16 * c];
#pragma unroll
        for (int r = 0; r < 4; ++r) acc2[c][r] = b;
    }
#pragma unroll
    for (int kk = 0; kk < 20; ++kk) {
        f4 a[4];
#pragma unroll
        for (int q = 0; q < 4; ++q) a[q] = *(const f4*)&T[(4 * kk + q) * TP + 4 * tr];
#pragma unroll
        for (int c = 0; c < 5; ++c) {
            f4 w = *(const f4*)&W1T[(tc + 16 * c) * WP + 4 * kk];
#pragma unroll
            for (int q = 0; q < 4; ++q)
#pragma unroll
                for (int r = 0; r < 4; ++r) acc2[c][r] += a[q][r] * w[q];
        }
    }
    __syncthreads();
#pragma unroll
    for (int c = 0; c < 5; ++c) {
        f4 h;
#pragma unroll
        for (int r = 0; r < 4; ++r) h[r] = gelu_f(acc2[c][r]);
        *(f4*)&T[(tc + 16 * c) * TP + 4 * tr] = h;       // H2T
    }
    __syncthreads();

    float acc3[2][4];
#pragma unroll
    for (int c = 0; c < 2; ++c) {
        float b = bs[160 + tc + 16 * c];
#pragma unroll
        for (int r = 0; r < 4; ++r) acc3[c][r] = b;
    }
#pragma unroll
    for (int kk = 0; kk < 20; ++kk) {
        f4 a[4];
#pragma unroll
        for (int q = 0; q < 4; ++q) a[q] = *(const f4*)&T[(4 * kk + q) * TP + 4 * tr];
#pragma unroll
        for (int c = 0; c < 2; ++c) {
            f4 w = *(const f4*)&W2T[(tc + 16 * c) * WP + 4 * kk];
#pragma unroll
            for (int q = 0; q < 4; ++q)
#pragma unroll
                for (int r = 0; r < 4; ++r) acc3[c][r] += a[q][r] * w[q];
        }
    }
    __syncthreads();
#pragma unroll
    for (int c = 0; c < 2; ++c)
#pragma unroll
        for (int r = 0; r < 4; ++r)
            T[(4 * tr + r) * 33 + tc + 16 * c] = acc3[c][r];   // out[row][col]
    __syncthreads();
}

// ---- exclusive scan of counts -> offsets ----
__global__ __launch_bounds__(1024) void scan_kernel(
    const int* __restrict__ counts, int* __restrict__ offsets)
{
    __shared__ int buf[1024];
    __shared__ int carry;
    int t = threadIdx.x;
    if (t == 0) carry = 0;
    __syncthreads();
    for (int c = 0; c < N_PTS; c += 1024) {
        int vin = counts[c + t];
        buf[t] = vin;
        __syncthreads();
        for (int off = 1; off < 1024; off <<= 1) {
            int val = (t >= off) ? buf[t - off] : 0;
            __syncthreads();
            buf[t] += val;
            __syncthreads();
        }
        int incl = buf[t];
        offsets[c + t] = carry + incl - vin;
        __syncthreads();
        if (t == 1023) carry += incl;
        __syncthreads();
    }
}

// ---- projection ----
__global__ __launch_bounds__(256) void proj_kernel(
    const float* __restrict__ inp,
    const float* __restrict__ W0, const float* __restrict__ b0,
    const float* __restrict__ W1, const float* __restrict__ b1,
    float* __restrict__ f0)
{
    __shared__ float W0s[8 * 64];
    __shared__ float W1s[64 * OUTD];
    __shared__ float xs[32 * 8];
    __shared__ float H[32 * 64];
    const int t = threadIdx.x;
    const int r0 = blockIdx.x * 32;
    for (int idx = t; idx < 512; idx += 256) W0s[idx] = W0[idx];
    for (int idx = t; idx < 64 * OUTD; idx += 256) W1s[idx] = W1[idx];
    xs[t] = inp[r0 * 8 + t];
    __syncthreads();
#pragma unroll
    for (int p = 0; p < 8; ++p) {
        int o = t + 256 * p, r = o >> 6, col = o & 63;
        float s = b0[col];
#pragma unroll
        for (int k = 0; k < 8; ++k) s += xs[r * 8 + k] * W0s[k * 64 + col];
        H[o] = gelu_f(s);
    }
    __syncthreads();
#pragma unroll
    for (int p = 0; p < 4; ++p) {
        int o = t + 256 * p, r = o >> 5, c = o & 31;
        float s = b1[c];
#pragma unroll
        for (int k = 0; k < 64; ++k) s += H[r * 64 + k] * W1s[k * OUTD + c];
        int row = r0 + r;
        int n = row / 3, v = row - n * 3;
        f0[(((size_t)v << 13) + n) * OUTD + c] = s;
    }
}

// ---- edge MLP + owner-computes segment mean: block owns PB points ----
__global__ __launch_bounds__(256, 2) void agg_kernel(
    const float* __restrict__ grid_in, const float* __restrict__ f0,
    const int* __restrict__ nbr_index, const int* __restrict__ offsets,
    const int* __restrict__ counts,
    const float* __restrict__ W0g, const float* __restrict__ b0g,
    const float* __restrict__ W1g, const float* __restrict__ b1g,
    const float* __restrict__ W2g, const float* __restrict__ b2g,
    float* __restrict__ f1)
{
    __shared__ __attribute__((aligned(16))) float T[D1 * TP];
    __shared__ __attribute__((aligned(16))) float W0T[D1 * 36];
    __shared__ __attribute__((aligned(16))) float W1T[D1 * WP];
    __shared__ __attribute__((aligned(16))) float W2T[OUTD * WP];
    __shared__ float bs[192];
    __shared__ float accH[2][VARS * PB * 33];
    __shared__ int jb[64], keyb[64];
    __shared__ float sxb[64], syb[64];
    __shared__ int offs[PB + 1];
    __shared__ float px[PB * 2];
    __shared__ float invb[PB];

    const int t = threadIdx.x;
    const int p0 = blockIdx.x * PB;

    stage_weights(W0T, W1T, W2T, bs, W0g, b0g, W1g, b1g, W2g, b2g, t);
    if (t < PB) {
        offs[t] = offsets[p0 + t];
        int c = counts[p0 + t];
        invb[t] = 1.0f / (float)(c > 1 ? c : 1);
    }
    if (t == 0) offs[PB] = offsets[p0 + PB - 1] + counts[p0 + PB - 1];
    if (t < PB * 2) px[t] = grid_in[p0 * 2 + t];
    for (int idx = t; idx < 2 * VARS * PB * 33; idx += 256)
        ((float*)accH)[idx] = 0.0f;
    __syncthreads();

    const int e0 = offs[0];
    const int cntT = offs[PB] - e0;
    const int Rb = VARS * cntT;
    const int ntiles = (Rb + 63) / 64;

    for (int tile = 0; tile < ntiles; ++tile) {
        const int r0 = tile * 64;
        if (t < 64) {
            int row = r0 + t, key = -1, j = 0;
            float sx = 0.f, sy = 0.f;
            if (row < Rb) {
                int v = (row >= 2 * cntT) ? 2 : ((row >= cntT) ? 1 : 0);
                int e = e0 + row - v * cntT;
                j = nbr_index[e];
                int lp = (e >= offs[1]) + (e >= offs[2]) + (e >= offs[3]);
                key = v * PB + lp;
                sx = px[2 * lp]; sy = px[2 * lp + 1];
            }
            jb[t] = j; keyb[t] = key; sxb[t] = sx; syb[t] = sy;
        }
        __syncthreads();
        for (int idx = t; idx < 64 * 9; idx += 256) {
            int e = idx / 9, c = idx - e * 9;
            f4 val = {0.f, 0.f, 0.f, 0.f};
            int key = keyb[e];
            if (key >= 0) {
                int j = jb[e];
                if (c == 0) {
                    val[0] = grid_in[2 * j]; val[1] = grid_in[2 * j + 1];
                    val[2] = sxb[e];         val[3] = syb[e];
                } else {
                    int v = key >> 2;   // PB==4
                    val = *(const f4*)&f0[(((size_t)v << 13) + j) * OUTD + 4 * (c - 1)];
                }
            }
            T[(4 * c + 0) * TP + e] = val[0];
            T[(4 * c + 1) * TP + e] = val[1];
            T[(4 * c + 2) * TP + e] = val[2];
            T[(4 * c + 3) * TP + e] = val[3];
        }
        mlp_tile(T, W0T, W1T, W2T, bs, t);
        // accumulate: lanes 0..31 handle rows 0..31, lanes 32..63 rows 32..63
        if (t < 64) {
            int half = t >> 5, col = t & 31;
            float* acc = accH[half];
            int eb = half * 32;
#pragma unroll 1
            for (int e = eb; e < eb + 32; ++e) {
                int k = keyb[e];
                if (k >= 0) acc[k * 33 + col] += T[e * 33 + col];
            }
        }
        __syncthreads();   // protect keyb/T before next tile
    }

    for (int idx = t; idx < VARS * PB * OUTD; idx += 256) {
        int key = idx >> 5, c = idx & 31;
        int v = key >> 2, lp = key & 3;
        size_t o = (((size_t)v << 13) + p0 + lp) * OUTD + c;
        f1[o] = (accH[0][key * 33 + c] + accH[1][key * 33 + c]) * invb[lp] + f0[o];
    }
}

// ---- kNN MLP + mean: block owns 2 output points (60 rows, one tile) ----
__global__ __launch_bounds__(256, 2) void last_kernel(
    const float* __restrict__ grid_in, const float* __restrict__ grid_out,
    const float* __restrict__ f1, const int* __restrict__ nbr_last,
    const float* __restrict__ W0g, const float* __restrict__ b0g,
    const float* __restrict__ W1g, const float* __restrict__ b1g,
    const float* __restrict__ W2g, const float* __restrict__ b2g,
    float* __restrict__ out)
{
    __shared__ __attribute__((aligned(16))) float T[D1 * TP];
    __shared__ __attribute__((aligned(16))) float W0T[D1 * 36];
    __shared__ __attribute__((aligned(16))) float W1T[D1 * WP];
    __shared__ __attribute__((aligned(16))) float W2T[OUTD * WP];
    __shared__ float bs[192];
    __shared__ int jb[64], keyb[64];
    __shared__ float sxb[64], syb[64];

    const int t = threadIdx.x;
    const int m0 = blockIdx.x * 2;

    stage_weights(W0T, W1T, W2T, bs, W0g, b0g, W1g, b1g, W2g, b2g, t);
    if (t < 64) {
        int key = -1, j = 0;
        float sx = 0.f, sy = 0.f;
        if (t < 60) {
            int lp = t / 30, rr = t - 30 * lp;
            int v = rr / KLAST, kk = rr - v * KLAST;
            int m = m0 + lp;
            j = nbr_last[m * KLAST + kk];
            key = v;                       // var id (for f-gather)
            sx = grid_out[2 * m]; sy = grid_out[2 * m + 1];
        }
        jb[t] = j; keyb[t] = key; sxb[t] = sx; syb[t] = sy;
    }
    __syncthreads();
    for (int idx = t; idx < 64 * 9; idx += 256) {
        int e = idx / 9, c = idx - e * 9;
        f4 val = {0.f, 0.f, 0.f, 0.f};
        int key = keyb[e];
        if (key >= 0) {
            int j = jb[e];
            if (c == 0) {
                val[0] = grid_in[2 * j]; val[1] = grid_in[2 * j + 1];
                val[2] = sxb[e];         val[3] = syb[e];
            } else {
                val = *(const f4*)&f1[(((size_t)key << 13) + j) * OUTD + 4 * (c - 1)];
            }
        }
        T[(4 * c + 0) * TP + e] = val[0];
        T[(4 * c + 1) * TP + e] = val[1];
        T[(4 * c + 2) * TP + e] = val[2];
        T[(4 * c + 3) * TP + e] = val[3];
    }
    mlp_tile(T, W0T, W1T, W2T, bs, t);
    // mean over KLAST, plain store: 6 groups (lp,v) x 32 cols = 192 lanes
    if (t < 192) {
        int g = t >> 5, c = t & 31;
        int lp = g / VARS, v = g - lp * VARS;
        float s = 0.f;
#pragma unroll
        for (int k = 0; k < KLAST; ++k)
            s += T[(lp * 30 + v * KLAST + k) * 33 + c];
        out[(((size_t)(m0 + lp)) * VARS + v) * OUTD + c] = s * (1.0f / KLAST);
    }
}

extern "C" void kernel_launch(void* const* d_in, const int* in_sizes, int n_in,
                              void* d_out, int out_size, void* d_ws, size_t ws_size,
                              hipStream_t stream) {
    const float* inp      = (const float*)d_in[0];
    const float* grid_in  = (const float*)d_in[1];
    const float* grid_out = (const float*)d_in[2];
    const float* pW0 = (const float*)d_in[3];
    const float* pb0 = (const float*)d_in[4];
    const float* pW1 = (const float*)d_in[5];
    const float* pb1 = (const float*)d_in[6];
    const float* i0W0 = (const float*)d_in[7];
    const float* i0b0 = (const float*)d_in[8];
    const float* i0W1 = (const float*)d_in[9];
    const float* i0b1 = (const float*)d_in[10];
    const float* i0W2 = (const float*)d_in[11];
    const float* i0b2 = (const float*)d_in[12];
    const float* i1W0 = (const float*)d_in[13];
    const float* i1b0 = (const float*)d_in[14];
    const float* i1W1 = (const float*)d_in[15];
    const float* i1b1 = (const float*)d_in[16];
    const float* i1W2 = (const float*)d_in[17];
    const float* i1b2 = (const float*)d_in[18];
    const int* nbr_index  = (const int*)d_in[19];
    const int* nbr_counts = (const int*)d_in[21];
    const int* nbr_last   = (const int*)d_in[22];

    float* f0    = (float*)d_ws;                          // 3*8192*32
    float* f1    = f0 + (size_t)VARS * N_PTS * OUTD;      // 3*8192*32
    int* offsets = (int*)(f1 + (size_t)VARS * N_PTS * OUTD);

    proj_kernel<<<(N_PTS * VARS) / 32, 256, 0, stream>>>(inp, pW0, pb0, pW1, pb1, f0);
    scan_kernel<<<1, 1024, 0, stream>>>(nbr_counts, offsets);
    agg_kernel<<<N_PTS / PB, 256, 0, stream>>>(grid_in, f0, nbr_index, offsets, nbr_counts,
                                               i0W0, i0b0, i0W1, i0b1, i0W2, i0b2, f1);
    last_kernel<<<M_PTS / 2, 256, 0, stream>>>(grid_in, grid_out, f1, nbr_last,
                                               i1W0, i1b0, i1W1, i1b1, i1W2, i1b2,
                                               (float*)d_out);
}

// Round 4
// 663.209 us; speedup vs baseline: 17.4982x; 17.4982x over previous
//
#include <hip/hip_runtime.h>
#include <math.h>

#define N_PTS 8192
#define M_PTS 2048
#define KLAST 10
#define VARS 3
#define OUTD 32
#define D1 80
#define D2 80
#define TP 68      // T pitch (floats)
#define WP 84      // W1T/W2T pitch
#define PB 4       // points per agg block

typedef float f4 __attribute__((ext_vector_type(4)));

__device__ __forceinline__ float gelu_f(float x) {
    return 0.5f * x * (1.0f + erff(x * 0.70710678118654752f));
}

// stage weights (transposed into LDS) + biases; caller barriers after.
__device__ __forceinline__ void stage_weights(
    float* W0T, float* W1T, float* W2T, float* bs,
    const float* __restrict__ W0g, const float* __restrict__ b0g,
    const float* __restrict__ W1g, const float* __restrict__ b1g,
    const float* __restrict__ W2g, const float* __restrict__ b2g, int t)
{
    for (int idx = t; idx < 36 * D1; idx += 256) {
        int k = idx / D1, col = idx - k * D1;
        W0T[col * 36 + k] = W0g[idx];                    // coalesced read
    }
    for (int idx = t; idx < D1 * D2; idx += 256) {
        int k = idx / D2, col = idx - k * D2;
        W1T[col * WP + k] = W1g[idx];
    }
    for (int idx = t; idx < D2 * OUTD; idx += 256) {
        int k = idx / OUTD, col = idx - k * OUTD;
        W2T[col * WP + k] = W2g[idx];
    }
    for (int idx = t; idx < 192; idx += 256)
        bs[idx] = (idx < 80) ? b0g[idx] : (idx < 160 ? b1g[idx - 80] : b2g[idx - 160]);
}

// 64-row tile MLP. On entry T rows 0..35 hold transposed activations (pitch TP).
// On exit T holds out[64][33]. Weights pre-staged. Barriers inside.
// NOTE: kk loops are "#pragma unroll 1" ON PURPOSE — full unroll made the
// scheduler hoist dozens of ds_read_b128 into temporaries -> scratch spills
// -> 33 GB of HBM spill traffic (rounds 2-3). Keep them rolled.
__device__ __forceinline__ void mlp_tile(
    float* T, const float* W0T, const float* W1T, const float* W2T,
    const float* bs, int t)
{
    const int tc = t & 15, tr = t >> 4;
    __syncthreads();                                     // staging of T done

    float acc1[5][4];
#pragma unroll
    for (int c = 0; c < 5; ++c) {
        float b = bs[tc + 16 * c];
#pragma unroll
        for (int r = 0; r < 4; ++r) acc1[c][r] = b;
    }
#pragma unroll 1
    for (int kk = 0; kk < 9; ++kk) {
        f4 a[4];
#pragma unroll
        for (int q = 0; q < 4; ++q) a[q] = *(const f4*)&T[(4 * kk + q) * TP + 4 * tr];
#pragma unroll
        for (int c = 0; c < 5; ++c) {
            f4 w = *(const f4*)&W0T[(tc + 16 * c) * 36 + 4 * kk];
#pragma unroll
            for (int q = 0; q < 4; ++q)
#pragma unroll
                for (int r = 0; r < 4; ++r) acc1[c][r] += a[q][r] * w[q];
        }
    }
    __syncthreads();
#pragma unroll
    for (int c = 0; c < 5; ++c) {
        f4 h;
#pragma unroll
        for (int r = 0; r < 4; ++r) h[r] = gelu_f(acc1[c][r]);
        *(f4*)&T[(tc + 16 * c) * TP + 4 * tr] = h;       // H1T
    }
    __syncthreads();

    float acc2[5][4];
#pragma unroll
    for (int c = 0; c < 5; ++c) {
        float b = bs[80 + tc + 16 * c];
#pragma unroll
        for (int r = 0; r < 4; ++r) acc2[c][r] = b;
    }
#pragma unroll 1
    for (int kk = 0; kk < 20; ++kk) {
        f4 a[4];
#pragma unroll
        for (int q = 0; q < 4; ++q) a[q] = *(const f4*)&T[(4 * kk + q) * TP + 4 * tr];
#pragma unroll
        for (int c = 0; c < 5; ++c) {
            f4 w = *(const f4*)&W1T[(tc + 16 * c) * WP + 4 * kk];
#pragma unroll
            for (int q = 0; q < 4; ++q)
#pragma unroll
                for (int r = 0; r < 4; ++r) acc2[c][r] += a[q][r] * w[q];
        }
    }
    __syncthreads();
#pragma unroll
    for (int c = 0; c < 5; ++c) {
        f4 h;
#pragma unroll
        for (int r = 0; r < 4; ++r) h[r] = gelu_f(acc2[c][r]);
        *(f4*)&T[(tc + 16 * c) * TP + 4 * tr] = h;       // H2T
    }
    __syncthreads();

    float acc3[2][4];
#pragma unroll
    for (int c = 0; c < 2; ++c) {
        float b = bs[160 + tc + 16 * c];
#pragma unroll
        for (int r = 0; r < 4; ++r) acc3[c][r] = b;
    }
#pragma unroll 1
    for (int kk = 0; kk < 20; ++kk) {
        f4 a[4];
#pragma unroll
        for (int q = 0; q < 4; ++q) a[q] = *(const f4*)&T[(4 * kk + q) * TP + 4 * tr];
#pragma unroll
        for (int c = 0; c < 2; ++c) {
            f4 w = *(const f4*)&W2T[(tc + 16 * c) * WP + 4 * kk];
#pragma unroll
            for (int q = 0; q < 4; ++q)
#pragma unroll
                for (int r = 0; r < 4; ++r) acc3[c][r] += a[q][r] * w[q];
        }
    }
    __syncthreads();
#pragma unroll
    for (int c = 0; c < 2; ++c)
#pragma unroll
        for (int r = 0; r < 4; ++r)
            T[(4 * tr + r) * 33 + tc + 16 * c] = acc3[c][r];   // out[row][col]
    __syncthreads();
}

// ---- exclusive scan of counts -> offsets ----
__global__ __launch_bounds__(1024) void scan_kernel(
    const int* __restrict__ counts, int* __restrict__ offsets)
{
    __shared__ int buf[1024];
    __shared__ int carry;
    int t = threadIdx.x;
    if (t == 0) carry = 0;
    __syncthreads();
    for (int c = 0; c < N_PTS; c += 1024) {
        int vin = counts[c + t];
        buf[t] = vin;
        __syncthreads();
        for (int off = 1; off < 1024; off <<= 1) {
            int val = (t >= off) ? buf[t - off] : 0;
            __syncthreads();
            buf[t] += val;
            __syncthreads();
        }
        int incl = buf[t];
        offsets[c + t] = carry + incl - vin;
        __syncthreads();
        if (t == 1023) carry += incl;
        __syncthreads();
    }
}

// ---- projection ----
__global__ __launch_bounds__(256) void proj_kernel(
    const float* __restrict__ inp,
    const float* __restrict__ W0, const float* __restrict__ b0,
    const float* __restrict__ W1, const float* __restrict__ b1,
    float* __restrict__ f0)
{
    __shared__ float W0s[8 * 64];
    __shared__ float W1s[64 * OUTD];
    __shared__ float xs[32 * 8];
    __shared__ float H[32 * 64];
    const int t = threadIdx.x;
    const int r0 = blockIdx.x * 32;
    for (int idx = t; idx < 512; idx += 256) W0s[idx] = W0[idx];
    for (int idx = t; idx < 64 * OUTD; idx += 256) W1s[idx] = W1[idx];
    xs[t] = inp[r0 * 8 + t];
    __syncthreads();
#pragma unroll 1
    for (int p = 0; p < 8; ++p) {
        int o = t + 256 * p, r = o >> 6, col = o & 63;
        float s = b0[col];
#pragma unroll
        for (int k = 0; k < 8; ++k) s += xs[r * 8 + k] * W0s[k * 64 + col];
        H[o] = gelu_f(s);
    }
    __syncthreads();
#pragma unroll 1
    for (int p = 0; p < 4; ++p) {
        int o = t + 256 * p, r = o >> 5, c = o & 31;
        float s = b1[c];
#pragma unroll 8
        for (int k = 0; k < 64; ++k) s += H[r * 64 + k] * W1s[k * OUTD + c];
        int row = r0 + r;
        int n = row / 3, v = row - n * 3;
        f0[(((size_t)v << 13) + n) * OUTD + c] = s;
    }
}

// ---- edge MLP + owner-computes segment mean: block owns PB points ----
__global__ __launch_bounds__(256, 2) void agg_kernel(
    const float* __restrict__ grid_in, const float* __restrict__ f0,
    const int* __restrict__ nbr_index, const int* __restrict__ offsets,
    const int* __restrict__ counts,
    const float* __restrict__ W0g, const float* __restrict__ b0g,
    const float* __restrict__ W1g, const float* __restrict__ b1g,
    const float* __restrict__ W2g, const float* __restrict__ b2g,
    float* __restrict__ f1)
{
    __shared__ __attribute__((aligned(16))) float T[D1 * TP];
    __shared__ __attribute__((aligned(16))) float W0T[D1 * 36];
    __shared__ __attribute__((aligned(16))) float W1T[D1 * WP];
    __shared__ __attribute__((aligned(16))) float W2T[OUTD * WP];
    __shared__ float bs[192];
    __shared__ float accH[2][VARS * PB * 33];
    __shared__ int jb[64], keyb[64];
    __shared__ float sxb[64], syb[64];
    __shared__ int offs[PB + 1];
    __shared__ float px[PB * 2];
    __shared__ float invb[PB];

    const int t = threadIdx.x;
    const int p0 = blockIdx.x * PB;

    stage_weights(W0T, W1T, W2T, bs, W0g, b0g, W1g, b1g, W2g, b2g, t);
    if (t < PB) {
        offs[t] = offsets[p0 + t];
        int c = counts[p0 + t];
        invb[t] = 1.0f / (float)(c > 1 ? c : 1);
    }
    if (t == 0) offs[PB] = offsets[p0 + PB - 1] + counts[p0 + PB - 1];
    if (t < PB * 2) px[t] = grid_in[p0 * 2 + t];
    for (int idx = t; idx < 2 * VARS * PB * 33; idx += 256)
        ((float*)accH)[idx] = 0.0f;
    __syncthreads();

    const int e0 = offs[0];
    const int cntT = offs[PB] - e0;
    const int Rb = VARS * cntT;
    const int ntiles = (Rb + 63) / 64;

    for (int tile = 0; tile < ntiles; ++tile) {
        const int r0 = tile * 64;
        if (t < 64) {
            int row = r0 + t, key = -1, j = 0;
            float sx = 0.f, sy = 0.f;
            if (row < Rb) {
                int v = (row >= 2 * cntT) ? 2 : ((row >= cntT) ? 1 : 0);
                int e = e0 + row - v * cntT;
                j = nbr_index[e];
                int lp = (e >= offs[1]) + (e >= offs[2]) + (e >= offs[3]);
                key = v * PB + lp;
                sx = px[2 * lp]; sy = px[2 * lp + 1];
            }
            jb[t] = j; keyb[t] = key; sxb[t] = sx; syb[t] = sy;
        }
        __syncthreads();
        for (int idx = t; idx < 64 * 9; idx += 256) {
            int e = idx / 9, c = idx - e * 9;
            f4 val = {0.f, 0.f, 0.f, 0.f};
            int key = keyb[e];
            if (key >= 0) {
                int j = jb[e];
                if (c == 0) {
                    val[0] = grid_in[2 * j]; val[1] = grid_in[2 * j + 1];
                    val[2] = sxb[e];         val[3] = syb[e];
                } else {
                    int v = key >> 2;   // PB==4
                    val = *(const f4*)&f0[(((size_t)v << 13) + j) * OUTD + 4 * (c - 1)];
                }
            }
            T[(4 * c + 0) * TP + e] = val[0];
            T[(4 * c + 1) * TP + e] = val[1];
            T[(4 * c + 2) * TP + e] = val[2];
            T[(4 * c + 3) * TP + e] = val[3];
        }
        mlp_tile(T, W0T, W1T, W2T, bs, t);
        // accumulate: lanes 0..31 handle rows 0..31, lanes 32..63 rows 32..63
        if (t < 64) {
            int half = t >> 5, col = t & 31;
            float* acc = accH[half];
            int eb = half * 32;
#pragma unroll 1
            for (int e = eb; e < eb + 32; ++e) {
                int k = keyb[e];
                if (k >= 0) acc[k * 33 + col] += T[e * 33 + col];
            }
        }
        __syncthreads();   // protect keyb/T before next tile
    }

    for (int idx = t; idx < VARS * PB * OUTD; idx += 256) {
        int key = idx >> 5, c = idx & 31;
        int v = key >> 2, lp = key & 3;
        size_t o = (((size_t)v << 13) + p0 + lp) * OUTD + c;
        f1[o] = (accH[0][key * 33 + c] + accH[1][key * 33 + c]) * invb[lp] + f0[o];
    }
}

// ---- kNN MLP + mean: block owns 2 output points (60 rows, one tile) ----
__global__ __launch_bounds__(256, 2) void last_kernel(
    const float* __restrict__ grid_in, const float* __restrict__ grid_out,
    const float* __restrict__ f1, const int* __restrict__ nbr_last,
    const float* __restrict__ W0g, const float* __restrict__ b0g,
    const float* __restrict__ W1g, const float* __restrict__ b1g,
    const float* __restrict__ W2g, const float* __restrict__ b2g,
    float* __restrict__ out)
{
    __shared__ __attribute__((aligned(16))) float T[D1 * TP];
    __shared__ __attribute__((aligned(16))) float W0T[D1 * 36];
    __shared__ __attribute__((aligned(16))) float W1T[D1 * WP];
    __shared__ __attribute__((aligned(16))) float W2T[OUTD * WP];
    __shared__ float bs[192];
    __shared__ int jb[64], keyb[64];
    __shared__ float sxb[64], syb[64];

    const int t = threadIdx.x;
    const int m0 = blockIdx.x * 2;

    stage_weights(W0T, W1T, W2T, bs, W0g, b0g, W1g, b1g, W2g, b2g, t);
    if (t < 64) {
        int key = -1, j = 0;
        float sx = 0.f, sy = 0.f;
        if (t < 60) {
            int lp = t / 30, rr = t - 30 * lp;
            int v = rr / KLAST, kk = rr - v * KLAST;
            int m = m0 + lp;
            j = nbr_last[m * KLAST + kk];
            key = v;                       // var id (for f-gather)
            sx = grid_out[2 * m]; sy = grid_out[2 * m + 1];
        }
        jb[t] = j; keyb[t] = key; sxb[t] = sx; syb[t] = sy;
    }
    __syncthreads();
    for (int idx = t; idx < 64 * 9; idx += 256) {
        int e = idx / 9, c = idx - e * 9;
        f4 val = {0.f, 0.f, 0.f, 0.f};
        int key = keyb[e];
        if (key >= 0) {
            int j = jb[e];
            if (c == 0) {
                val[0] = grid_in[2 * j]; val[1] = grid_in[2 * j + 1];
                val[2] = sxb[e];         val[3] = syb[e];
            } else {
                val = *(const f4*)&f1[(((size_t)key << 13) + j) * OUTD + 4 * (c - 1)];
            }
        }
        T[(4 * c + 0) * TP + e] = val[0];
        T[(4 * c + 1) * TP + e] = val[1];
        T[(4 * c + 2) * TP + e] = val[2];
        T[(4 * c + 3) * TP + e] = val[3];
    }
    mlp_tile(T, W0T, W1T, W2T, bs, t);
    // mean over KLAST, plain store: 6 groups (lp,v) x 32 cols = 192 lanes
    if (t < 192) {
        int g = t >> 5, c = t & 31;
        int lp = g / VARS, v = g - lp * VARS;
        float s = 0.f;
#pragma unroll
        for (int k = 0; k < KLAST; ++k)
            s += T[(lp * 30 + v * KLAST + k) * 33 + c];
        out[(((size_t)(m0 + lp)) * VARS + v) * OUTD + c] = s * (1.0f / KLAST);
    }
}

extern "C" void kernel_launch(void* const* d_in, const int* in_sizes, int n_in,
                              void* d_out, int out_size, void* d_ws, size_t ws_size,
                              hipStream_t stream) {
    const float* inp      = (const float*)d_in[0];
    const float* grid_in  = (const float*)d_in[1];
    const float* grid_out = (const float*)d_in[2];
    const float* pW0 = (const float*)d_in[3];
    const float* pb0 = (const float*)d_in[4];
    const float* pW1 = (const float*)d_in[5];
    const float* pb1 = (const float*)d_in[6];
    const float* i0W0 = (const float*)d_in[7];
    const float* i0b0 = (const float*)d_in[8];
    const float* i0W1 = (const float*)d_in[9];
    const float* i0b1 = (const float*)d_in[10];
    const float* i0W2 = (const float*)d_in[11];
    const float* i0b2 = (const float*)d_in[12];
    const float* i1W0 = (const float*)d_in[13];
    const float* i1b0 = (const float*)d_in[14];
    const float* i1W1 = (const float*)d_in[15];
    const float* i1b1 = (const float*)d_in[16];
    const float* i1W2 = (const float*)d_in[17];
    const float* i1b2 = (const float*)d_in[18];
    const int* nbr_index  = (const int*)d_in[19];
    const int* nbr_counts = (const int*)d_in[21];
    const int* nbr_last   = (const int*)d_in[22];

    float* f0    = (float*)d_ws;                          // 3*8192*32
    float* f1    = f0 + (size_t)VARS * N_PTS * OUTD;      // 3*8192*32
    int* offsets = (int*)(f1 + (size_t)VARS * N_PTS * OUTD);

    proj_kernel<<<(N_PTS * VARS) / 32, 256, 0, stream>>>(inp, pW0, pb0, pW1, pb1, f0);
    scan_kernel<<<1, 1024, 0, stream>>>(nbr_counts, offsets);
    agg_kernel<<<N_PTS / PB, 256, 0, stream>>>(grid_in, f0, nbr_index, offsets, nbr_counts,
                                               i0W0, i0b0, i0W1, i0b1, i0W2, i0b2, f1);
    last_kernel<<<M_PTS / 2, 256, 0, stream>>>(grid_in, grid_out, f1, nbr_last,
                                               i1W0, i1b0, i1W1, i1b1, i1W2, i1b2,
                                               (float*)d_out);
}

// Round 5
// 517.726 us; speedup vs baseline: 22.4152x; 1.2810x over previous
//
#include <hip/hip_runtime.h>
#include <math.h>

#define N_PTS 8192
#define M_PTS 2048
#define KLAST 10
#define VARS 3
#define OUTD 32
#define D1 80
#define D2 80
#define PB 8          // points per agg block
#define LPTS 4        // output points per last block
#define TPCH 104      // Tb row pitch (bf16 elems); K up to 96 + 16B-align, 4-way bank worst
#define W0P 72        // W0 K-pitch (K=36 padded to 64)
#define W1P 104       // W1/W2 K-pitch (K=80 padded to 96)

typedef float f4 __attribute__((ext_vector_type(4)));
typedef short bf16x8 __attribute__((ext_vector_type(8)));

__device__ __forceinline__ float gelu_f(float x) {
    return 0.5f * x * (1.0f + erff(x * 0.70710678118654752f));
}
__device__ __forceinline__ unsigned short f2bf(float x) {
    unsigned int u = __float_as_uint(x);
    u += 0x7FFF + ((u >> 16) & 1);          // round-to-nearest-even
    return (unsigned short)(u >> 16);
}
__device__ __forceinline__ float bf2f(unsigned short h) {
    return __uint_as_float(((unsigned int)h) << 16);
}

// Stage split (hi+lo bf16) weights transposed [col][k] with zero-padded K.
// W2 planes staged into Tb (exactly fills it); caller barriers, preloads
// W2 frags to VGPRs, barriers again before Tb is reused for activations.
__device__ __forceinline__ void stage_split_weights(
    unsigned short* W0h, unsigned short* W0l,
    unsigned short* W1h, unsigned short* W1l,
    unsigned short* Tb, float* bs,
    const float* __restrict__ W0g, const float* __restrict__ b0g,
    const float* __restrict__ W1g, const float* __restrict__ b1g,
    const float* __restrict__ W2g, const float* __restrict__ b2g, int t)
{
    for (int idx = t; idx < D1 * W0P; idx += 256) {
        int col = idx / W0P, k = idx - col * W0P;
        float w = (k < 36) ? W0g[k * D1 + col] : 0.0f;
        unsigned short h = f2bf(w);
        W0h[idx] = h; W0l[idx] = f2bf(w - bf2f(h));
    }
    for (int idx = t; idx < D1 * W1P; idx += 256) {
        int col = idx / W1P, k = idx - col * W1P;
        float w = (k < D2) ? W1g[k * D1 + col] : 0.0f;
        unsigned short h = f2bf(w);
        W1h[idx] = h; W1l[idx] = f2bf(w - bf2f(h));
    }
    for (int idx = t; idx < OUTD * W1P; idx += 256) {
        int col = idx / W1P, k = idx - col * W1P;
        float w = (k < D2) ? W2g[k * OUTD + col] : 0.0f;
        unsigned short h = f2bf(w);
        Tb[idx] = h; Tb[OUTD * W1P + idx] = f2bf(w - bf2f(h));
    }
    for (int idx = t; idx < 192; idx += 256)
        bs[idx] = (idx < 80) ? b0g[idx] : (idx < 160 ? b1g[idx - 80] : b2g[idx - 160]);
}

// Per-wave 16-row chunk MLP. Trow = this lane's activation row in LDS.
// MFMA operands swapped: A = weights [col][k], B = acts [row][k]; D lane reg r
// holds (col = cb*16 + quad*4 + r, row = lm) -> b64-packable H writes.
// cb loops are unroll-1 ON PURPOSE (full unroll caused scratch spills, R2/R3).
__device__ __forceinline__ void mlp_chunk(
    unsigned short* Trow,
    const unsigned short* W0h, const unsigned short* W0l,
    const unsigned short* W1h, const unsigned short* W1l,
    const bf16x8* w2f, const float* bs, int lm, int quad)
{
    // ---- L1: 36(pad 64) -> 80, gelu ----
    bf16x8 b1f[2];
    b1f[0] = *(const bf16x8*)&Trow[quad * 8];
    b1f[1] = *(const bf16x8*)&Trow[32 + quad * 8];
#pragma unroll 1
    for (int cb = 0; cb < 5; ++cb) {
        f4 acc = *(const f4*)&bs[cb * 16 + quad * 4];
#pragma unroll
        for (int ks = 0; ks < 2; ++ks) {
            bf16x8 ah = *(const bf16x8*)&W0h[(cb * 16 + lm) * W0P + ks * 32 + quad * 8];
            bf16x8 al = *(const bf16x8*)&W0l[(cb * 16 + lm) * W0P + ks * 32 + quad * 8];
            acc = __builtin_amdgcn_mfma_f32_16x16x32_bf16(ah, b1f[ks], acc, 0, 0, 0);
            acc = __builtin_amdgcn_mfma_f32_16x16x32_bf16(al, b1f[ks], acc, 0, 0, 0);
        }
        unsigned int pa = f2bf(gelu_f(acc.x)) | ((unsigned int)f2bf(gelu_f(acc.y)) << 16);
        unsigned int pb = f2bf(gelu_f(acc.z)) | ((unsigned int)f2bf(gelu_f(acc.w)) << 16);
        *(int2*)&Trow[cb * 16 + quad * 4] = make_int2((int)pa, (int)pb);
    }
    // ---- L2: 80(pad 96) -> 80, gelu ----
    bf16x8 b2f[3];
    b2f[0] = *(const bf16x8*)&Trow[quad * 8];
    b2f[1] = *(const bf16x8*)&Trow[32 + quad * 8];
    b2f[2] = *(const bf16x8*)&Trow[64 + quad * 8];
#pragma unroll 1
    for (int cb = 0; cb < 5; ++cb) {
        f4 acc = *(const f4*)&bs[80 + cb * 16 + quad * 4];
#pragma unroll
        for (int ks = 0; ks < 3; ++ks) {
            bf16x8 ah = *(const bf16x8*)&W1h[(cb * 16 + lm) * W1P + ks * 32 + quad * 8];
            bf16x8 al = *(const bf16x8*)&W1l[(cb * 16 + lm) * W1P + ks * 32 + quad * 8];
            acc = __builtin_amdgcn_mfma_f32_16x16x32_bf16(ah, b2f[ks], acc, 0, 0, 0);
            acc = __builtin_amdgcn_mfma_f32_16x16x32_bf16(al, b2f[ks], acc, 0, 0, 0);
        }
        unsigned int pa = f2bf(gelu_f(acc.x)) | ((unsigned int)f2bf(gelu_f(acc.y)) << 16);
        unsigned int pb = f2bf(gelu_f(acc.z)) | ((unsigned int)f2bf(gelu_f(acc.w)) << 16);
        *(int2*)&Trow[cb * 16 + quad * 4] = make_int2((int)pa, (int)pb);
    }
    // ---- L3: 80(pad 96) -> 32, fp32 out overlaid into Trow ----
    bf16x8 b3f[3];
    b3f[0] = *(const bf16x8*)&Trow[quad * 8];
    b3f[1] = *(const bf16x8*)&Trow[32 + quad * 8];
    b3f[2] = *(const bf16x8*)&Trow[64 + quad * 8];
    float* po = (float*)Trow;
#pragma unroll 1
    for (int cb = 0; cb < 2; ++cb) {
        f4 acc = *(const f4*)&bs[160 + cb * 16 + quad * 4];
#pragma unroll
        for (int ks = 0; ks < 3; ++ks) {
            acc = __builtin_amdgcn_mfma_f32_16x16x32_bf16(w2f[(cb * 3 + ks) * 2 + 0], b3f[ks], acc, 0, 0, 0);
            acc = __builtin_amdgcn_mfma_f32_16x16x32_bf16(w2f[(cb * 3 + ks) * 2 + 1], b3f[ks], acc, 0, 0, 0);
        }
        *(f4*)&po[cb * 16 + quad * 4] = acc;
    }
}

// ---- exclusive scan of counts -> offsets ----
__global__ __launch_bounds__(1024) void scan_kernel(
    const int* __restrict__ counts, int* __restrict__ offsets)
{
    __shared__ int buf[1024];
    __shared__ int carry;
    int t = threadIdx.x;
    if (t == 0) carry = 0;
    __syncthreads();
    for (int c = 0; c < N_PTS; c += 1024) {
        int vin = counts[c + t];
        buf[t] = vin;
        __syncthreads();
        for (int off = 1; off < 1024; off <<= 1) {
            int val = (t >= off) ? buf[t - off] : 0;
            __syncthreads();
            buf[t] += val;
            __syncthreads();
        }
        int incl = buf[t];
        offsets[c + t] = carry + incl - vin;
        __syncthreads();
        if (t == 1023) carry += incl;
        __syncthreads();
    }
}

// ---- projection (unchanged from R4) ----
__global__ __launch_bounds__(256) void proj_kernel(
    const float* __restrict__ inp,
    const float* __restrict__ W0, const float* __restrict__ b0,
    const float* __restrict__ W1, const float* __restrict__ b1,
    float* __restrict__ f0)
{
    __shared__ float W0s[8 * 64];
    __shared__ float W1s[64 * OUTD];
    __shared__ float xs[32 * 8];
    __shared__ float H[32 * 64];
    const int t = threadIdx.x;
    const int r0 = blockIdx.x * 32;
    for (int idx = t; idx < 512; idx += 256) W0s[idx] = W0[idx];
    for (int idx = t; idx < 64 * OUTD; idx += 256) W1s[idx] = W1[idx];
    xs[t] = inp[r0 * 8 + t];
    __syncthreads();
#pragma unroll 1
    for (int p = 0; p < 8; ++p) {
        int o = t + 256 * p, r = o >> 6, col = o & 63;
        float s = b0[col];
#pragma unroll
        for (int k = 0; k < 8; ++k) s += xs[r * 8 + k] * W0s[k * 64 + col];
        H[o] = gelu_f(s);
    }
    __syncthreads();
#pragma unroll 1
    for (int p = 0; p < 4; ++p) {
        int o = t + 256 * p, r = o >> 5, c = o & 31;
        float s = b1[c];
#pragma unroll 8
        for (int k = 0; k < 64; ++k) s += H[r * 64 + k] * W1s[k * OUTD + c];
        int row = r0 + r;
        int n = row / 3, v = row - n * 3;
        f0[(((size_t)v << 13) + n) * OUTD + c] = s;
    }
}

// ---- edge MLP + owner-computes segment mean, MFMA version ----
__global__ __launch_bounds__(256, 2) void agg_kernel(
    const float* __restrict__ grid_in, const float* __restrict__ f0,
    const int* __restrict__ nbr_index, const int* __restrict__ offsets,
    const int* __restrict__ counts,
    const float* __restrict__ W0g, const float* __restrict__ b0g,
    const float* __restrict__ W1g, const float* __restrict__ b1g,
    const float* __restrict__ W2g, const float* __restrict__ b2g,
    float* __restrict__ f1)
{
    __shared__ __attribute__((aligned(16))) unsigned short Tb[64 * TPCH];
    __shared__ __attribute__((aligned(16))) unsigned short W0h[D1 * W0P], W0l[D1 * W0P];
    __shared__ __attribute__((aligned(16))) unsigned short W1h[D1 * W1P], W1l[D1 * W1P];
    __shared__ __attribute__((aligned(16))) float bs[192];
    __shared__ __attribute__((aligned(16))) float accH[VARS * PB * 33];
    __shared__ int offs[PB + 1];
    __shared__ float px[PB * 2];
    __shared__ float invb[PB];

    const int t = threadIdx.x;
    const int lane = t & 63, wave = t >> 6;
    const int lm = lane & 15, quad = lane >> 4;
    const int p0 = blockIdx.x * PB;

    stage_split_weights(W0h, W0l, W1h, W1l, Tb, bs, W0g, b0g, W1g, b1g, W2g, b2g, t);
    if (t < PB) {
        offs[t] = offsets[p0 + t];
        int c = counts[p0 + t];
        invb[t] = 1.0f / (float)(c > 1 ? c : 1);
    }
    if (t == PB) offs[PB] = offsets[p0 + PB - 1] + counts[p0 + PB - 1];
    if (t < PB * 2) px[t] = grid_in[p0 * 2 + t];
    for (int idx = t; idx < VARS * PB * 33; idx += 256) accH[idx] = 0.0f;
    __syncthreads();

    bf16x8 w2f[12];
#pragma unroll
    for (int cb = 0; cb < 2; ++cb)
#pragma unroll
        for (int ks = 0; ks < 3; ++ks)
#pragma unroll
            for (int pl = 0; pl < 2; ++pl)
                w2f[(cb * 3 + ks) * 2 + pl] =
                    *(const bf16x8*)&Tb[pl * (OUTD * W1P) + (cb * 16 + lm) * W1P + ks * 32 + quad * 8];
    __syncthreads();

    const int e0 = offs[0];
    const int cntT = offs[PB] - e0;
    const int Rb = VARS * cntT;
    const int nch = (Rb + 15) >> 4;

    unsigned short* Tw = Tb + (wave * 16) * TPCH;         // wave-private 16 rows
    unsigned short* Trow = Tb + (wave * 16 + lm) * TPCH;  // this lane's row

    for (int ch = wave; ch < nch; ch += 4) {
        const int rowbase = ch << 4;
        int myrow = rowbase + lm;
        int myj = 0, myv = 0, mykey = -1;
        float msx = 0.0f, msy = 0.0f;
        if (myrow < Rb) {
            myv = (myrow >= 2 * cntT) ? 2 : ((myrow >= cntT) ? 1 : 0);
            int e = e0 + myrow - myv * cntT;
            myj = nbr_index[e];
            int lp = 0;
#pragma unroll
            for (int l = 1; l < PB; ++l) lp += (e >= offs[l]);
            mykey = myv * PB + lp;
            msx = px[2 * lp]; msy = px[2 * lp + 1];
        }
        // zero pad region k 36..103 of own rows (NaN-safe MFMA pad)
        for (int it = lane; it < 16 * 9; it += 64) {
            int el = it / 9, c = it - el * 9;
            if (c == 0) *(int2*)&Tw[el * TPCH + 36] = make_int2(0, 0);
            else        *(int4*)&Tw[el * TPCH + 40 + 8 * (c - 1)] = make_int4(0, 0, 0, 0);
        }
        // gather agg features, pack to bf16, k 0..35
        for (int it = lane; it < 16 * 9; it += 64) {
            int el = it / 9, c = it - el * 9;
            int k2 = __shfl(mykey, el);
            int j  = __shfl(myj, el);
            int v  = __shfl(myv, el);
            float fx = __shfl(msx, el), fy = __shfl(msy, el);
            float x0 = 0.f, x1 = 0.f, x2 = 0.f, x3 = 0.f;
            if (k2 >= 0) {
                if (c == 0) { x0 = grid_in[2 * j]; x1 = grid_in[2 * j + 1]; x2 = fx; x3 = fy; }
                else {
                    f4 vv = *(const f4*)&f0[((((size_t)v) << 13) + j) * OUTD + 4 * (c - 1)];
                    x0 = vv.x; x1 = vv.y; x2 = vv.z; x3 = vv.w;
                }
            }
            unsigned int pa = f2bf(x0) | ((unsigned int)f2bf(x1) << 16);
            unsigned int pb = f2bf(x2) | ((unsigned int)f2bf(x3) << 16);
            *(int2*)&Tw[el * TPCH + 4 * c] = make_int2((int)pa, (int)pb);
        }
        mlp_chunk(Trow, W0h, W0l, W1h, W1l, w2f, bs, lm, quad);
        // keyed reduction of own 16 rows into block accumulator (LDS atomics)
        int col = lane & 31, eo = lane >> 5;
        for (int e2 = eo; e2 < 16; e2 += 2) {
            int k = __shfl(mykey, e2);
            if (k >= 0)
                atomicAdd(&accH[k * 33 + col],
                          ((const float*)(Tb + (size_t)(wave * 16 + e2) * TPCH))[col]);
        }
    }
    __syncthreads();
    for (int idx = t; idx < VARS * PB * OUTD; idx += 256) {
        int key = idx >> 5, c = idx & 31;
        int v = key >> 3, lp = key & 7;
        size_t o = ((((size_t)v) << 13) + p0 + lp) * OUTD + c;
        f1[o] = accH[key * 33 + c] * invb[lp] + f0[o];
    }
}

// ---- kNN MLP + mean over K, MFMA version ----
__global__ __launch_bounds__(256, 2) void last_kernel(
    const float* __restrict__ grid_in, const float* __restrict__ grid_out,
    const float* __restrict__ f1, const int* __restrict__ nbr_last,
    const float* __restrict__ W0g, const float* __restrict__ b0g,
    const float* __restrict__ W1g, const float* __restrict__ b1g,
    const float* __restrict__ W2g, const float* __restrict__ b2g,
    float* __restrict__ out)
{
    __shared__ __attribute__((aligned(16))) unsigned short Tb[64 * TPCH];
    __shared__ __attribute__((aligned(16))) unsigned short W0h[D1 * W0P], W0l[D1 * W0P];
    __shared__ __attribute__((aligned(16))) unsigned short W1h[D1 * W1P], W1l[D1 * W1P];
    __shared__ __attribute__((aligned(16))) float bs[192];
    __shared__ __attribute__((aligned(16))) float accH[LPTS * VARS * 33];

    const int t = threadIdx.x;
    const int lane = t & 63, wave = t >> 6;
    const int lm = lane & 15, quad = lane >> 4;
    const int m0 = blockIdx.x * LPTS;

    stage_split_weights(W0h, W0l, W1h, W1l, Tb, bs, W0g, b0g, W1g, b1g, W2g, b2g, t);
    for (int idx = t; idx < LPTS * VARS * 33; idx += 256) accH[idx] = 0.0f;
    __syncthreads();

    bf16x8 w2f[12];
#pragma unroll
    for (int cb = 0; cb < 2; ++cb)
#pragma unroll
        for (int ks = 0; ks < 3; ++ks)
#pragma unroll
            for (int pl = 0; pl < 2; ++pl)
                w2f[(cb * 3 + ks) * 2 + pl] =
                    *(const bf16x8*)&Tb[pl * (OUTD * W1P) + (cb * 16 + lm) * W1P + ks * 32 + quad * 8];
    __syncthreads();

    const int Rb = LPTS * VARS * KLAST;   // 120
    const int nch = (Rb + 15) >> 4;       // 8

    unsigned short* Tw = Tb + (wave * 16) * TPCH;
    unsigned short* Trow = Tb + (wave * 16 + lm) * TPCH;

    for (int ch = wave; ch < nch; ch += 4) {
        const int rowbase = ch << 4;
        int myrow = rowbase + lm;
        int myj = 0, myv = 0, mykey = -1;
        float msx = 0.0f, msy = 0.0f;
        if (myrow < Rb) {
            int lp = myrow / 30, rr = myrow - lp * 30;
            myv = rr / KLAST; int kk = rr - myv * KLAST;
            myj = nbr_last[(m0 + lp) * KLAST + kk];
            mykey = lp * VARS + myv;
            msx = grid_out[2 * (m0 + lp)]; msy = grid_out[2 * (m0 + lp) + 1];
        }
        for (int it = lane; it < 16 * 9; it += 64) {
            int el = it / 9, c = it - el * 9;
            if (c == 0) *(int2*)&Tw[el * TPCH + 36] = make_int2(0, 0);
            else        *(int4*)&Tw[el * TPCH + 40 + 8 * (c - 1)] = make_int4(0, 0, 0, 0);
        }
        for (int it = lane; it < 16 * 9; it += 64) {
            int el = it / 9, c = it - el * 9;
            int k2 = __shfl(mykey, el);
            int j  = __shfl(myj, el);
            int v  = __shfl(myv, el);
            float fx = __shfl(msx, el), fy = __shfl(msy, el);
            float x0 = 0.f, x1 = 0.f, x2 = 0.f, x3 = 0.f;
            if (k2 >= 0) {
                if (c == 0) { x0 = grid_in[2 * j]; x1 = grid_in[2 * j + 1]; x2 = fx; x3 = fy; }
                else {
                    f4 vv = *(const f4*)&f1[((((size_t)v) << 13) + j) * OUTD + 4 * (c - 1)];
                    x0 = vv.x; x1 = vv.y; x2 = vv.z; x3 = vv.w;
                }
            }
            unsigned int pa = f2bf(x0) | ((unsigned int)f2bf(x1) << 16);
            unsigned int pb = f2bf(x2) | ((unsigned int)f2bf(x3) << 16);
            *(int2*)&Tw[el * TPCH + 4 * c] = make_int2((int)pa, (int)pb);
        }
        mlp_chunk(Trow, W0h, W0l, W1h, W1l, w2f, bs, lm, quad);
        int col = lane & 31, eo = lane >> 5;
        for (int e2 = eo; e2 < 16; e2 += 2) {
            int k = __shfl(mykey, e2);
            if (k >= 0)
                atomicAdd(&accH[k * 33 + col],
                          ((const float*)(Tb + (size_t)(wave * 16 + e2) * TPCH))[col]);
        }
    }
    __syncthreads();
    for (int idx = t; idx < LPTS * VARS * OUTD; idx += 256) {
        int key = idx >> 5, c = idx & 31;
        int lp = key / VARS, v = key - lp * VARS;
        out[((size_t)(m0 + lp) * VARS + v) * OUTD + c] = accH[key * 33 + c] * (1.0f / KLAST);
    }
}

extern "C" void kernel_launch(void* const* d_in, const int* in_sizes, int n_in,
                              void* d_out, int out_size, void* d_ws, size_t ws_size,
                              hipStream_t stream) {
    const float* inp      = (const float*)d_in[0];
    const float* grid_in  = (const float*)d_in[1];
    const float* grid_out = (const float*)d_in[2];
    const float* pW0 = (const float*)d_in[3];
    const float* pb0 = (const float*)d_in[4];
    const float* pW1 = (const float*)d_in[5];
    const float* pb1 = (const float*)d_in[6];
    const float* i0W0 = (const float*)d_in[7];
    const float* i0b0 = (const float*)d_in[8];
    const float* i0W1 = (const float*)d_in[9];
    const float* i0b1 = (const float*)d_in[10];
    const float* i0W2 = (const float*)d_in[11];
    const float* i0b2 = (const float*)d_in[12];
    const float* i1W0 = (const float*)d_in[13];
    const float* i1b0 = (const float*)d_in[14];
    const float* i1W1 = (const float*)d_in[15];
    const float* i1b1 = (const float*)d_in[16];
    const float* i1W2 = (const float*)d_in[17];
    const float* i1b2 = (const float*)d_in[18];
    const int* nbr_index  = (const int*)d_in[19];
    const int* nbr_counts = (const int*)d_in[21];
    const int* nbr_last   = (const int*)d_in[22];

    float* f0    = (float*)d_ws;                          // 3*8192*32
    float* f1    = f0 + (size_t)VARS * N_PTS * OUTD;      // 3*8192*32
    int* offsets = (int*)(f1 + (size_t)VARS * N_PTS * OUTD);

    proj_kernel<<<(N_PTS * VARS) / 32, 256, 0, stream>>>(inp, pW0, pb0, pW1, pb1, f0);
    scan_kernel<<<1, 1024, 0, stream>>>(nbr_counts, offsets);
    agg_kernel<<<N_PTS / PB, 256, 0, stream>>>(grid_in, f0, nbr_index, offsets, nbr_counts,
                                               i0W0, i0b0, i0W1, i0b1, i0W2, i0b2, f1);
    last_kernel<<<M_PTS / LPTS, 256, 0, stream>>>(grid_in, grid_out, f1, nbr_last,
                                                  i1W0, i1b0, i1W1, i1b1, i1W2, i1b2,
                                                  (float*)d_out);
}

// Round 6
// 398.052 us; speedup vs baseline: 29.1544x; 1.3007x over previous
//
#include <hip/hip_runtime.h>
#include <math.h>

#define N_PTS 8192
#define M_PTS 2048
#define KLAST 10
#define VARS 3
#define OUTD 32
#define D1 80
#define D2 80
#define PB 16         // points per agg block (16 waves, 1024 threads)
#define LPTS 8        // output points per last block
#define NT 1024       // threads per mega-block
#define NWAVES 16
#define TPCH 104      // Tb row pitch (bf16 elems); 208 B row -> 2-way banks on b128
#define W0P 72        // W0 K-pitch (K=36 padded to 64)
#define W1P 104       // W1/W2 K-pitch (K=80 padded to 96)

typedef float f4 __attribute__((ext_vector_type(4)));
typedef short bf16x8 __attribute__((ext_vector_type(8)));

// tanh-approx gelu (max |err| vs exact erf-gelu ~3e-4; abs threshold 1.21e-2).
// Branch-free, inf-safe: tanh(t) = 1 - 2*rcp(exp(2t)+1).
__device__ __forceinline__ float gelu_f(float x) {
    float x2 = x * x;
    float t = x * (0.7978845608028654f + 0.0356774081f * x2);
    float u = __expf(2.0f * t);
    float th = 1.0f - 2.0f * __builtin_amdgcn_rcpf(u + 1.0f);
    return 0.5f * x * (1.0f + th);
}
__device__ __forceinline__ unsigned short f2bf(float x) {
    unsigned int u = __float_as_uint(x);
    u += 0x7FFF + ((u >> 16) & 1);          // round-to-nearest-even
    return (unsigned short)(u >> 16);
}
__device__ __forceinline__ float bf2f(unsigned short h) {
    return __uint_as_float(((unsigned int)h) << 16);
}

// Stage split (hi+lo bf16) weights transposed [col][k] with zero-padded K.
// W2 planes staged into Tb; caller barriers, preloads W2 frags to VGPRs,
// barriers again before Tb is reused for activations.
__device__ __forceinline__ void stage_split_weights(
    unsigned short* W0h, unsigned short* W0l,
    unsigned short* W1h, unsigned short* W1l,
    unsigned short* Tb, float* bs,
    const float* __restrict__ W0g, const float* __restrict__ b0g,
    const float* __restrict__ W1g, const float* __restrict__ b1g,
    const float* __restrict__ W2g, const float* __restrict__ b2g, int t)
{
    for (int idx = t; idx < D1 * W0P; idx += NT) {
        int col = idx / W0P, k = idx - col * W0P;
        float w = (k < 36) ? W0g[k * D1 + col] : 0.0f;
        unsigned short h = f2bf(w);
        W0h[idx] = h; W0l[idx] = f2bf(w - bf2f(h));
    }
    for (int idx = t; idx < D1 * W1P; idx += NT) {
        int col = idx / W1P, k = idx - col * W1P;
        float w = (k < D2) ? W1g[k * D1 + col] : 0.0f;
        unsigned short h = f2bf(w);
        W1h[idx] = h; W1l[idx] = f2bf(w - bf2f(h));
    }
    for (int idx = t; idx < OUTD * W1P; idx += NT) {
        int col = idx / W1P, k = idx - col * W1P;
        float w = (k < D2) ? W2g[k * OUTD + col] : 0.0f;
        unsigned short h = f2bf(w);
        Tb[idx] = h; Tb[OUTD * W1P + idx] = f2bf(w - bf2f(h));
    }
    for (int idx = t; idx < 192; idx += NT)
        bs[idx] = (idx < 80) ? b0g[idx] : (idx < 160 ? b1g[idx - 80] : b2g[idx - 160]);
}

// Per-wave 16-row chunk MLP. Trow = this lane's activation row in LDS.
// A = weights [col][k], B = acts [row][k]; D lane reg r = (col=cb*16+quad*4+r,
// row=lm) -> b64-packable H writes. cb loops unroll-1 ON PURPOSE (full unroll
// caused scratch spills -> 33 GB HBM traffic, rounds 2-3).
__device__ __forceinline__ void mlp_chunk(
    unsigned short* Trow,
    const unsigned short* W0h, const unsigned short* W0l,
    const unsigned short* W1h, const unsigned short* W1l,
    const bf16x8* w2f, const float* bs, int lm, int quad)
{
    // ---- L1: 36(pad 64) -> 80, gelu ----
    bf16x8 b1f[2];
    b1f[0] = *(const bf16x8*)&Trow[quad * 8];
    b1f[1] = *(const bf16x8*)&Trow[32 + quad * 8];
#pragma unroll 1
    for (int cb = 0; cb < 5; ++cb) {
        f4 acc = *(const f4*)&bs[cb * 16 + quad * 4];
#pragma unroll
        for (int ks = 0; ks < 2; ++ks) {
            bf16x8 ah = *(const bf16x8*)&W0h[(cb * 16 + lm) * W0P + ks * 32 + quad * 8];
            bf16x8 al = *(const bf16x8*)&W0l[(cb * 16 + lm) * W0P + ks * 32 + quad * 8];
            acc = __builtin_amdgcn_mfma_f32_16x16x32_bf16(ah, b1f[ks], acc, 0, 0, 0);
            acc = __builtin_amdgcn_mfma_f32_16x16x32_bf16(al, b1f[ks], acc, 0, 0, 0);
        }
        unsigned int pa = f2bf(gelu_f(acc.x)) | ((unsigned int)f2bf(gelu_f(acc.y)) << 16);
        unsigned int pb = f2bf(gelu_f(acc.z)) | ((unsigned int)f2bf(gelu_f(acc.w)) << 16);
        *(int2*)&Trow[cb * 16 + quad * 4] = make_int2((int)pa, (int)pb);
    }
    // ---- L2: 80(pad 96) -> 80, gelu ----
    bf16x8 b2f[3];
    b2f[0] = *(const bf16x8*)&Trow[quad * 8];
    b2f[1] = *(const bf16x8*)&Trow[32 + quad * 8];
    b2f[2] = *(const bf16x8*)&Trow[64 + quad * 8];
#pragma unroll 1
    for (int cb = 0; cb < 5; ++cb) {
        f4 acc = *(const f4*)&bs[80 + cb * 16 + quad * 4];
#pragma unroll
        for (int ks = 0; ks < 3; ++ks) {
            bf16x8 ah = *(const bf16x8*)&W1h[(cb * 16 + lm) * W1P + ks * 32 + quad * 8];
            bf16x8 al = *(const bf16x8*)&W1l[(cb * 16 + lm) * W1P + ks * 32 + quad * 8];
            acc = __builtin_amdgcn_mfma_f32_16x16x32_bf16(ah, b2f[ks], acc, 0, 0, 0);
            acc = __builtin_amdgcn_mfma_f32_16x16x32_bf16(al, b2f[ks], acc, 0, 0, 0);
        }
        unsigned int pa = f2bf(gelu_f(acc.x)) | ((unsigned int)f2bf(gelu_f(acc.y)) << 16);
        unsigned int pb = f2bf(gelu_f(acc.z)) | ((unsigned int)f2bf(gelu_f(acc.w)) << 16);
        *(int2*)&Trow[cb * 16 + quad * 4] = make_int2((int)pa, (int)pb);
    }
    // ---- L3: 80(pad 96) -> 32, fp32 out overlaid into Trow ----
    bf16x8 b3f[3];
    b3f[0] = *(const bf16x8*)&Trow[quad * 8];
    b3f[1] = *(const bf16x8*)&Trow[32 + quad * 8];
    b3f[2] = *(const bf16x8*)&Trow[64 + quad * 8];
    float* po = (float*)Trow;
#pragma unroll 1
    for (int cb = 0; cb < 2; ++cb) {
        f4 acc = *(const f4*)&bs[160 + cb * 16 + quad * 4];
#pragma unroll
        for (int ks = 0; ks < 3; ++ks) {
            acc = __builtin_amdgcn_mfma_f32_16x16x32_bf16(w2f[(cb * 3 + ks) * 2 + 0], b3f[ks], acc, 0, 0, 0);
            acc = __builtin_amdgcn_mfma_f32_16x16x32_bf16(w2f[(cb * 3 + ks) * 2 + 1], b3f[ks], acc, 0, 0, 0);
        }
        *(f4*)&po[cb * 16 + quad * 4] = acc;
    }
}

// ---- fast exclusive scan: 8 elems/thread + shfl wave scan (~2 us) ----
__global__ __launch_bounds__(1024) void scan_kernel(
    const int* __restrict__ counts, int* __restrict__ offsets)
{
    __shared__ int wtot[16], wexc[16];
    const int t = threadIdx.x, lane = t & 63, wave = t >> 6;
    int4 a = ((const int4*)counts)[2 * t];
    int4 b = ((const int4*)counts)[2 * t + 1];
    int c0 = a.x, c1 = a.y, c2 = a.z, c3 = a.w;
    int c4 = b.x, c5 = b.y, c6 = b.z, c7 = b.w;
    int e0 = 0, e1 = c0, e2 = e1 + c1, e3 = e2 + c2, e4 = e3 + c3;
    int e5 = e4 + c4, e6 = e5 + c5, e7 = e6 + c6;
    int s = e7 + c7;
    int x = s;
#pragma unroll
    for (int d = 1; d < 64; d <<= 1) {
        int y = __shfl_up(x, d);
        if (lane >= d) x += y;
    }
    if (lane == 63) wtot[wave] = x;
    int lane_base = x - s;
    __syncthreads();
    if (wave == 0 && lane < 16) {
        int v = wtot[lane];
        int xx = v;
#pragma unroll
        for (int d = 1; d < 16; d <<= 1) {
            int y = __shfl_up(xx, d);
            if (lane >= d) xx += y;
        }
        wexc[lane] = xx - v;
    }
    __syncthreads();
    int base = wexc[wave] + lane_base;
    ((int4*)offsets)[2 * t]     = make_int4(base + e0, base + e1, base + e2, base + e3);
    ((int4*)offsets)[2 * t + 1] = make_int4(base + e4, base + e5, base + e6, base + e7);
}

// ---- projection ----
__global__ __launch_bounds__(256) void proj_kernel(
    const float* __restrict__ inp,
    const float* __restrict__ W0, const float* __restrict__ b0,
    const float* __restrict__ W1, const float* __restrict__ b1,
    float* __restrict__ f0)
{
    __shared__ float W0s[8 * 64];
    __shared__ float W1s[64 * OUTD];
    __shared__ float xs[32 * 8];
    __shared__ float H[32 * 64];
    const int t = threadIdx.x;
    const int r0 = blockIdx.x * 32;
    for (int idx = t; idx < 512; idx += 256) W0s[idx] = W0[idx];
    for (int idx = t; idx < 64 * OUTD; idx += 256) W1s[idx] = W1[idx];
    xs[t] = inp[r0 * 8 + t];
    __syncthreads();
#pragma unroll 1
    for (int p = 0; p < 8; ++p) {
        int o = t + 256 * p, r = o >> 6, col = o & 63;
        float s = b0[col];
#pragma unroll
        for (int k = 0; k < 8; ++k) s += xs[r * 8 + k] * W0s[k * 64 + col];
        H[o] = gelu_f(s);
    }
    __syncthreads();
#pragma unroll 1
    for (int p = 0; p < 4; ++p) {
        int o = t + 256 * p, r = o >> 5, c = o & 31;
        float s = b1[c];
#pragma unroll 8
        for (int k = 0; k < 64; ++k) s += H[r * 64 + k] * W1s[k * OUTD + c];
        int row = r0 + r;
        int n = row / 3, v = row - n * 3;
        f0[(((size_t)v << 13) + n) * OUTD + c] = s;
    }
}

// ---- edge MLP + owner-computes segment mean; 16-wave mega-block ----
__global__ __launch_bounds__(1024, 4) void agg_kernel(
    const float* __restrict__ grid_in, const float* __restrict__ f0,
    const int* __restrict__ nbr_index, const int* __restrict__ offsets,
    const int* __restrict__ counts,
    const float* __restrict__ W0g, const float* __restrict__ b0g,
    const float* __restrict__ W1g, const float* __restrict__ b1g,
    const float* __restrict__ W2g, const float* __restrict__ b2g,
    float* __restrict__ f1)
{
    __shared__ __attribute__((aligned(16))) unsigned short Tb[NWAVES * 16 * TPCH];
    __shared__ __attribute__((aligned(16))) unsigned short W0h[D1 * W0P], W0l[D1 * W0P];
    __shared__ __attribute__((aligned(16))) unsigned short W1h[D1 * W1P], W1l[D1 * W1P];
    __shared__ __attribute__((aligned(16))) float bs[192];
    __shared__ __attribute__((aligned(16))) float accH[VARS * PB * 33];
    __shared__ int offs[PB + 1];
    __shared__ float px[PB * 2];
    __shared__ float invb[PB];

    const int t = threadIdx.x;
    const int lane = t & 63, wave = t >> 6;
    const int lm = lane & 15, quad = lane >> 4;
    const int p0 = blockIdx.x * PB;

    stage_split_weights(W0h, W0l, W1h, W1l, Tb, bs, W0g, b0g, W1g, b1g, W2g, b2g, t);
    if (t < PB) {
        offs[t] = offsets[p0 + t];
        int c = counts[p0 + t];
        invb[t] = 1.0f / (float)(c > 1 ? c : 1);
    }
    if (t == PB) offs[PB] = offsets[p0 + PB - 1] + counts[p0 + PB - 1];
    if (t >= 32 && t < 32 + PB * 2) px[t - 32] = grid_in[p0 * 2 + (t - 32)];
    for (int idx = t; idx < VARS * PB * 33; idx += NT) accH[idx] = 0.0f;
    __syncthreads();

    bf16x8 w2f[12];
#pragma unroll
    for (int cb = 0; cb < 2; ++cb)
#pragma unroll
        for (int ks = 0; ks < 3; ++ks)
#pragma unroll
            for (int pl = 0; pl < 2; ++pl)
                w2f[(cb * 3 + ks) * 2 + pl] =
                    *(const bf16x8*)&Tb[pl * (OUTD * W1P) + (cb * 16 + lm) * W1P + ks * 32 + quad * 8];
    __syncthreads();

    const int e0 = offs[0];
    const int cntT = offs[PB] - e0;
    const int Rb = VARS * cntT;
    const int nch = (Rb + 15) >> 4;

    unsigned short* Tw = Tb + (wave * 16) * TPCH;         // wave-private 16 rows
    unsigned short* Trow = Tb + (wave * 16 + lm) * TPCH;  // this lane's row

    for (int ch = wave; ch < nch; ch += NWAVES) {
        const int rowbase = ch << 4;
        int myrow = rowbase + lm;
        int myj = 0, myv = 0, mykey = -1;
        float msx = 0.0f, msy = 0.0f;
        if (myrow < Rb) {
            myv = (myrow >= 2 * cntT) ? 2 : ((myrow >= cntT) ? 1 : 0);
            int e = e0 + myrow - myv * cntT;
            myj = nbr_index[e];
            int lp = 0;
#pragma unroll
            for (int l = 1; l < PB; ++l) lp += (e >= offs[l]);
            mykey = myv * PB + lp;
            msx = px[2 * lp]; msy = px[2 * lp + 1];
        }
        // zero pad region k 36..103 of own rows (NaN-safe MFMA pad)
        for (int it = lane; it < 16 * 9; it += 64) {
            int el = it / 9, c = it - el * 9;
            if (c == 0) *(int2*)&Tw[el * TPCH + 36] = make_int2(0, 0);
            else        *(int4*)&Tw[el * TPCH + 40 + 8 * (c - 1)] = make_int4(0, 0, 0, 0);
        }
        // gather agg features, pack to bf16, k 0..35
        for (int it = lane; it < 16 * 9; it += 64) {
            int el = it / 9, c = it - el * 9;
            int k2 = __shfl(mykey, el);
            int j  = __shfl(myj, el);
            int v  = __shfl(myv, el);
            float fx = __shfl(msx, el), fy = __shfl(msy, el);
            float x0 = 0.f, x1 = 0.f, x2 = 0.f, x3 = 0.f;
            if (k2 >= 0) {
                if (c == 0) { x0 = grid_in[2 * j]; x1 = grid_in[2 * j + 1]; x2 = fx; x3 = fy; }
                else {
                    f4 vv = *(const f4*)&f0[((((size_t)v) << 13) + j) * OUTD + 4 * (c - 1)];
                    x0 = vv.x; x1 = vv.y; x2 = vv.z; x3 = vv.w;
                }
            }
            unsigned int pa = f2bf(x0) | ((unsigned int)f2bf(x1) << 16);
            unsigned int pb = f2bf(x2) | ((unsigned int)f2bf(x3) << 16);
            *(int2*)&Tw[el * TPCH + 4 * c] = make_int2((int)pa, (int)pb);
        }
        mlp_chunk(Trow, W0h, W0l, W1h, W1l, w2f, bs, lm, quad);
        // keyed reduction of own 16 rows into block accumulator (LDS atomics)
        int col = lane & 31, eo = lane >> 5;
        for (int e2 = eo; e2 < 16; e2 += 2) {
            int k = __shfl(mykey, e2);
            if (k >= 0)
                atomicAdd(&accH[k * 33 + col],
                          ((const float*)(Tb + (size_t)(wave * 16 + e2) * TPCH))[col]);
        }
    }
    __syncthreads();
    for (int idx = t; idx < VARS * PB * OUTD; idx += NT) {
        int key = idx >> 5, c = idx & 31;
        int v = key >> 4, lp = key & 15;      // PB == 16
        size_t o = ((((size_t)v) << 13) + p0 + lp) * OUTD + c;
        f1[o] = accH[key * 33 + c] * invb[lp] + f0[o];
    }
}

// ---- kNN MLP + mean over K; 16-wave mega-block ----
__global__ __launch_bounds__(1024, 4) void last_kernel(
    const float* __restrict__ grid_in, const float* __restrict__ grid_out,
    const float* __restrict__ f1, const int* __restrict__ nbr_last,
    const float* __restrict__ W0g, const float* __restrict__ b0g,
    const float* __restrict__ W1g, const float* __restrict__ b1g,
    const float* __restrict__ W2g, const float* __restrict__ b2g,
    float* __restrict__ out)
{
    __shared__ __attribute__((aligned(16))) unsigned short Tb[NWAVES * 16 * TPCH];
    __shared__ __attribute__((aligned(16))) unsigned short W0h[D1 * W0P], W0l[D1 * W0P];
    __shared__ __attribute__((aligned(16))) unsigned short W1h[D1 * W1P], W1l[D1 * W1P];
    __shared__ __attribute__((aligned(16))) float bs[192];
    __shared__ __attribute__((aligned(16))) float accH[LPTS * VARS * 33];

    const int t = threadIdx.x;
    const int lane = t & 63, wave = t >> 6;
    const int lm = lane & 15, quad = lane >> 4;
    const int m0 = blockIdx.x * LPTS;

    stage_split_weights(W0h, W0l, W1h, W1l, Tb, bs, W0g, b0g, W1g, b1g, W2g, b2g, t);
    for (int idx = t; idx < LPTS * VARS * 33; idx += NT) accH[idx] = 0.0f;
    __syncthreads();

    bf16x8 w2f[12];
#pragma unroll
    for (int cb = 0; cb < 2; ++cb)
#pragma unroll
        for (int ks = 0; ks < 3; ++ks)
#pragma unroll
            for (int pl = 0; pl < 2; ++pl)
                w2f[(cb * 3 + ks) * 2 + pl] =
                    *(const bf16x8*)&Tb[pl * (OUTD * W1P) + (cb * 16 + lm) * W1P + ks * 32 + quad * 8];
    __syncthreads();

    const int Rb = LPTS * VARS * KLAST;   // 240
    const int nch = (Rb + 15) >> 4;       // 15

    unsigned short* Tw = Tb + (wave * 16) * TPCH;
    unsigned short* Trow = Tb + (wave * 16 + lm) * TPCH;

    for (int ch = wave; ch < nch; ch += NWAVES) {
        const int rowbase = ch << 4;
        int myrow = rowbase + lm;
        int myj = 0, myv = 0, mykey = -1;
        float msx = 0.0f, msy = 0.0f;
        if (myrow < Rb) {
            int lp = myrow / 30, rr = myrow - lp * 30;
            myv = rr / KLAST; int kk = rr - myv * KLAST;
            myj = nbr_last[(m0 + lp) * KLAST + kk];
            mykey = lp * VARS + myv;
            msx = grid_out[2 * (m0 + lp)]; msy = grid_out[2 * (m0 + lp) + 1];
        }
        for (int it = lane; it < 16 * 9; it += 64) {
            int el = it / 9, c = it - el * 9;
            if (c == 0) *(int2*)&Tw[el * TPCH + 36] = make_int2(0, 0);
            else        *(int4*)&Tw[el * TPCH + 40 + 8 * (c - 1)] = make_int4(0, 0, 0, 0);
        }
        for (int it = lane; it < 16 * 9; it += 64) {
            int el = it / 9, c = it - el * 9;
            int k2 = __shfl(mykey, el);
            int j  = __shfl(myj, el);
            int v  = __shfl(myv, el);
            float fx = __shfl(msx, el), fy = __shfl(msy, el);
            float x0 = 0.f, x1 = 0.f, x2 = 0.f, x3 = 0.f;
            if (k2 >= 0) {
                if (c == 0) { x0 = grid_in[2 * j]; x1 = grid_in[2 * j + 1]; x2 = fx; x3 = fy; }
                else {
                    f4 vv = *(const f4*)&f1[((((size_t)v) << 13) + j) * OUTD + 4 * (c - 1)];
                    x0 = vv.x; x1 = vv.y; x2 = vv.z; x3 = vv.w;
                }
            }
            unsigned int pa = f2bf(x0) | ((unsigned int)f2bf(x1) << 16);
            unsigned int pb = f2bf(x2) | ((unsigned int)f2bf(x3) << 16);
            *(int2*)&Tw[el * TPCH + 4 * c] = make_int2((int)pa, (int)pb);
        }
        mlp_chunk(Trow, W0h, W0l, W1h, W1l, w2f, bs, lm, quad);
        int col = lane & 31, eo = lane >> 5;
        for (int e2 = eo; e2 < 16; e2 += 2) {
            int k = __shfl(mykey, e2);
            if (k >= 0)
                atomicAdd(&accH[k * 33 + col],
                          ((const float*)(Tb + (size_t)(wave * 16 + e2) * TPCH))[col]);
        }
    }
    __syncthreads();
    if (t < LPTS * VARS * OUTD) {
        int key = t >> 5, c = t & 31;
        int lp = key / VARS, v = key - lp * VARS;
        out[((size_t)(m0 + lp) * VARS + v) * OUTD + c] = accH[key * 33 + c] * (1.0f / KLAST);
    }
}

extern "C" void kernel_launch(void* const* d_in, const int* in_sizes, int n_in,
                              void* d_out, int out_size, void* d_ws, size_t ws_size,
                              hipStream_t stream) {
    const float* inp      = (const float*)d_in[0];
    const float* grid_in  = (const float*)d_in[1];
    const float* grid_out = (const float*)d_in[2];
    const float* pW0 = (const float*)d_in[3];
    const float* pb0 = (const float*)d_in[4];
    const float* pW1 = (const float*)d_in[5];
    const float* pb1 = (const float*)d_in[6];
    const float* i0W0 = (const float*)d_in[7];
    const float* i0b0 = (const float*)d_in[8];
    const float* i0W1 = (const float*)d_in[9];
    const float* i0b1 = (const float*)d_in[10];
    const float* i0W2 = (const float*)d_in[11];
    const float* i0b2 = (const float*)d_in[12];
    const float* i1W0 = (const float*)d_in[13];
    const float* i1b0 = (const float*)d_in[14];
    const float* i1W1 = (const float*)d_in[15];
    const float* i1b1 = (const float*)d_in[16];
    const float* i1W2 = (const float*)d_in[17];
    const float* i1b2 = (const float*)d_in[18];
    const int* nbr_index  = (const int*)d_in[19];
    const int* nbr_counts = (const int*)d_in[21];
    const int* nbr_last   = (const int*)d_in[22];

    float* f0    = (float*)d_ws;                          // 3*8192*32
    float* f1    = f0 + (size_t)VARS * N_PTS * OUTD;      // 3*8192*32
    int* offsets = (int*)(f1 + (size_t)VARS * N_PTS * OUTD);

    proj_kernel<<<(N_PTS * VARS) / 32, 256, 0, stream>>>(inp, pW0, pb0, pW1, pb1, f0);
    scan_kernel<<<1, 1024, 0, stream>>>(nbr_counts, offsets);
    agg_kernel<<<N_PTS / PB, NT, 0, stream>>>(grid_in, f0, nbr_index, offsets, nbr_counts,
                                              i0W0, i0b0, i0W1, i0b1, i0W2, i0b2, f1);
    last_kernel<<<M_PTS / LPTS, NT, 0, stream>>>(grid_in, grid_out, f1, nbr_last,
                                                 i1W0, i1b0, i1W1, i1b1, i1W2, i1b2,
                                                 (float*)d_out);
}

// Round 7
// 381.658 us; speedup vs baseline: 30.4067x; 1.0430x over previous
//
#include <hip/hip_runtime.h>
#include <math.h>

#define N_PTS 8192
#define M_PTS 2048
#define KLAST 10
#define VARS 3
#define OUTD 32
#define D1 80
#define D2 80
#define PB 16         // points per agg block (16 waves, 1024 threads)
#define LPTS 8        // output points per last block
#define NT 1024
#define NWAVES 16
#define TPCH 104      // Tb row pitch in bf16 (208 B: 52-dword stride -> 2-way banks)
#define W0P 72        // W0 K-pitch (K=64: feats 0..32, pos 32..36, pad ..64)
#define W1P 104       // W1/W2 K-pitch (K=80 padded to 96)
#define RP 40         // f0b/f1b record pitch in bf16 (80 B: [32 feats | ypos | pad])

typedef float f4 __attribute__((ext_vector_type(4)));
typedef short bf16x8 __attribute__((ext_vector_type(8)));

// tanh-approx gelu (max |err| ~3e-4; abs threshold 1.21e-2). Branch-free.
__device__ __forceinline__ float gelu_f(float x) {
    float x2 = x * x;
    float t = x * (0.7978845608028654f + 0.0356774081f * x2);
    float u = __expf(2.0f * t);
    float th = 1.0f - 2.0f * __builtin_amdgcn_rcpf(u + 1.0f);
    return 0.5f * x * (1.0f + th);
}
__device__ __forceinline__ unsigned short f2bf(float x) {
    unsigned int u = __float_as_uint(x);
    u += 0x7FFF + ((u >> 16) & 1);
    return (unsigned short)(u >> 16);
}
__device__ __forceinline__ float bf2f(unsigned short h) {
    return __uint_as_float(((unsigned int)h) << 16);
}

// Stage split (hi+lo bf16) weights transposed [col][k], K zero-padded.
// W0 k-order is REORDERED to match record layout: k 0..31 <- W0g rows 4..35
// (features), k 32..35 <- W0g rows 0..3 (y_pos, self_pos), k 36..63 <- 0.
// W2 planes staged into Tb; caller barriers, preloads w2f, barriers.
__device__ __forceinline__ void stage_split_weights(
    unsigned short* W0h, unsigned short* W0l,
    unsigned short* W1h, unsigned short* W1l,
    unsigned short* Tb, float* bs,
    const float* __restrict__ W0g, const float* __restrict__ b0g,
    const float* __restrict__ W1g, const float* __restrict__ b1g,
    const float* __restrict__ W2g, const float* __restrict__ b2g, int t)
{
    for (int idx = t; idx < D1 * W0P; idx += NT) {
        int col = idx / W0P, k = idx - col * W0P;
        float w = (k < 32) ? W0g[(k + 4) * D1 + col]
                           : ((k < 36) ? W0g[(k - 32) * D1 + col] : 0.0f);
        unsigned short h = f2bf(w);
        W0h[idx] = h; W0l[idx] = f2bf(w - bf2f(h));
    }
    for (int idx = t; idx < D1 * W1P; idx += NT) {
        int col = idx / W1P, k = idx - col * W1P;
        float w = (k < D2) ? W1g[k * D1 + col] : 0.0f;
        unsigned short h = f2bf(w);
        W1h[idx] = h; W1l[idx] = f2bf(w - bf2f(h));
    }
    for (int idx = t; idx < OUTD * W1P; idx += NT) {
        int col = idx / W1P, k = idx - col * W1P;
        float w = (k < D2) ? W2g[k * OUTD + col] : 0.0f;
        unsigned short h = f2bf(w);
        Tb[idx] = h; Tb[OUTD * W1P + idx] = f2bf(w - bf2f(h));
    }
    for (int idx = t; idx < 192; idx += NT)
        bs[idx] = (idx < 80) ? b0g[idx] : (idx < 160 ? b1g[idx - 80] : b2g[idx - 160]);
}

// Per-wave 16-row chunk MLP. L1 B-operands arrive IN REGISTERS (feats = record
// chunk quad, posf = quad0's [y0,y1,sx,sy,0..]); H1/H2 relayout via wave-private
// LDS rows (no barriers; same-wave DS ordering). Out = 32 floats at Trow[0..64)
// bf16 region. Pad [80..96) must be pre-zeroed once per wave (never rewritten).
// cb loops unroll-1 ON PURPOSE (full unroll -> scratch spills, rounds 2-3).
__device__ __forceinline__ void mlp_chunk(
    int4 featsi, int4 posfi, unsigned short* Trow,
    const unsigned short* W0h, const unsigned short* W0l,
    const unsigned short* W1h, const unsigned short* W1l,
    const bf16x8* w2f, const float* bs, int lm, int quad)
{
    bf16x8 b1f0 = *(bf16x8*)&featsi;
    bf16x8 b1f1 = *(bf16x8*)&posfi;
    // ---- L1: K=64 (feats+pos+pad) -> 80, gelu ----
#pragma unroll 1
    for (int cb = 0; cb < 5; ++cb) {
        f4 acc = *(const f4*)&bs[cb * 16 + quad * 4];
        bf16x8 ah0 = *(const bf16x8*)&W0h[(cb * 16 + lm) * W0P + quad * 8];
        bf16x8 al0 = *(const bf16x8*)&W0l[(cb * 16 + lm) * W0P + quad * 8];
        bf16x8 ah1 = *(const bf16x8*)&W0h[(cb * 16 + lm) * W0P + 32 + quad * 8];
        bf16x8 al1 = *(const bf16x8*)&W0l[(cb * 16 + lm) * W0P + 32 + quad * 8];
        acc = __builtin_amdgcn_mfma_f32_16x16x32_bf16(ah0, b1f0, acc, 0, 0, 0);
        acc = __builtin_amdgcn_mfma_f32_16x16x32_bf16(al0, b1f0, acc, 0, 0, 0);
        acc = __builtin_amdgcn_mfma_f32_16x16x32_bf16(ah1, b1f1, acc, 0, 0, 0);
        acc = __builtin_amdgcn_mfma_f32_16x16x32_bf16(al1, b1f1, acc, 0, 0, 0);
        unsigned int pa = f2bf(gelu_f(acc.x)) | ((unsigned int)f2bf(gelu_f(acc.y)) << 16);
        unsigned int pb = f2bf(gelu_f(acc.z)) | ((unsigned int)f2bf(gelu_f(acc.w)) << 16);
        *(int2*)&Trow[cb * 16 + quad * 4] = make_int2((int)pa, (int)pb);
    }
    // ---- L2: 80(pad 96) -> 80, gelu ----
    bf16x8 b2f[3];
    b2f[0] = *(const bf16x8*)&Trow[quad * 8];
    b2f[1] = *(const bf16x8*)&Trow[32 + quad * 8];
    b2f[2] = *(const bf16x8*)&Trow[64 + quad * 8];
#pragma unroll 1
    for (int cb = 0; cb < 5; ++cb) {
        f4 acc = *(const f4*)&bs[80 + cb * 16 + quad * 4];
#pragma unroll
        for (int ks = 0; ks < 3; ++ks) {
            bf16x8 ah = *(const bf16x8*)&W1h[(cb * 16 + lm) * W1P + ks * 32 + quad * 8];
            bf16x8 al = *(const bf16x8*)&W1l[(cb * 16 + lm) * W1P + ks * 32 + quad * 8];
            acc = __builtin_amdgcn_mfma_f32_16x16x32_bf16(ah, b2f[ks], acc, 0, 0, 0);
            acc = __builtin_amdgcn_mfma_f32_16x16x32_bf16(al, b2f[ks], acc, 0, 0, 0);
        }
        unsigned int pa = f2bf(gelu_f(acc.x)) | ((unsigned int)f2bf(gelu_f(acc.y)) << 16);
        unsigned int pb = f2bf(gelu_f(acc.z)) | ((unsigned int)f2bf(gelu_f(acc.w)) << 16);
        *(int2*)&Trow[cb * 16 + quad * 4] = make_int2((int)pa, (int)pb);
    }
    // ---- L3: 80(pad 96) -> 32, fp32 out at Trow floats [0..32) ----
    bf16x8 b3f[3];
    b3f[0] = *(const bf16x8*)&Trow[quad * 8];
    b3f[1] = *(const bf16x8*)&Trow[32 + quad * 8];
    b3f[2] = *(const bf16x8*)&Trow[64 + quad * 8];
    float* po = (float*)Trow;
#pragma unroll 1
    for (int cb = 0; cb < 2; ++cb) {
        f4 acc = *(const f4*)&bs[160 + cb * 16 + quad * 4];
#pragma unroll
        for (int ks = 0; ks < 3; ++ks) {
            acc = __builtin_amdgcn_mfma_f32_16x16x32_bf16(w2f[(cb * 3 + ks) * 2 + 0], b3f[ks], acc, 0, 0, 0);
            acc = __builtin_amdgcn_mfma_f32_16x16x32_bf16(w2f[(cb * 3 + ks) * 2 + 1], b3f[ks], acc, 0, 0, 0);
        }
        *(f4*)&po[cb * 16 + quad * 4] = acc;
    }
}

// ---- fast exclusive scan ----
__global__ __launch_bounds__(1024) void scan_kernel(
    const int* __restrict__ counts, int* __restrict__ offsets)
{
    __shared__ int wtot[16], wexc[16];
    const int t = threadIdx.x, lane = t & 63, wave = t >> 6;
    int4 a = ((const int4*)counts)[2 * t];
    int4 b = ((const int4*)counts)[2 * t + 1];
    int e1 = a.x, e2 = e1 + a.y, e3 = e2 + a.z, e4 = e3 + a.w;
    int e5 = e4 + b.x, e6 = e5 + b.y, e7 = e6 + b.z;
    int s = e7 + b.w;
    int x = s;
#pragma unroll
    for (int d = 1; d < 64; d <<= 1) {
        int y = __shfl_up(x, d);
        if (lane >= d) x += y;
    }
    if (lane == 63) wtot[wave] = x;
    int lane_base = x - s;
    __syncthreads();
    if (wave == 0 && lane < 16) {
        int v = wtot[lane];
        int xx = v;
#pragma unroll
        for (int d = 1; d < 16; d <<= 1) {
            int y = __shfl_up(xx, d);
            if (lane >= d) xx += y;
        }
        wexc[lane] = xx - v;
    }
    __syncthreads();
    int base = wexc[wave] + lane_base;
    ((int4*)offsets)[2 * t]     = make_int4(base, base + e1, base + e2, base + e3);
    ((int4*)offsets)[2 * t + 1] = make_int4(base + e4, base + e5, base + e6, base + e7);
}

// ---- projection -> bf16 records f0b[(v<<13)+n]: [32 feats | ypos] ----
__global__ __launch_bounds__(256) void proj_kernel(
    const float* __restrict__ inp, const float* __restrict__ grid_in,
    const float* __restrict__ W0, const float* __restrict__ b0,
    const float* __restrict__ W1, const float* __restrict__ b1,
    unsigned short* __restrict__ f0b)
{
    __shared__ float W0s[8 * 64];
    __shared__ float W1s[64 * OUTD];
    __shared__ float xs[32 * 8];
    __shared__ float H[32 * 64];
    const int t = threadIdx.x;
    const int r0 = blockIdx.x * 32;
    for (int idx = t; idx < 512; idx += 256) W0s[idx] = W0[idx];
    for (int idx = t; idx < 64 * OUTD; idx += 256) W1s[idx] = W1[idx];
    xs[t] = inp[r0 * 8 + t];
    if (t < 32) {   // pos record for row r0+t
        int row = r0 + t, n = row / 3, v = row - n * 3;
        float gx = grid_in[2 * n], gy = grid_in[2 * n + 1];
        unsigned int pk = f2bf(gx) | ((unsigned int)f2bf(gy) << 16);
        *(int*)(f0b + ((size_t)(v << 13) + n) * RP + 32) = (int)pk;
    }
    __syncthreads();
#pragma unroll 1
    for (int p = 0; p < 8; ++p) {
        int o = t + 256 * p, r = o >> 6, col = o & 63;
        float s = b0[col];
#pragma unroll
        for (int k = 0; k < 8; ++k) s += xs[r * 8 + k] * W0s[k * 64 + col];
        H[o] = gelu_f(s);
    }
    __syncthreads();
#pragma unroll 1
    for (int p = 0; p < 4; ++p) {
        int o = t + 256 * p, r = o >> 5, c = o & 31;
        float s = b1[c];
#pragma unroll 8
        for (int k = 0; k < 64; ++k) s += H[r * 64 + k] * W1s[k * OUTD + c];
        int row = r0 + r;
        int n = row / 3, v = row - n * 3;
        f0b[((size_t)(v << 13) + n) * RP + c] = f2bf(s);
    }
}

// ---- edge MLP + owner-computes segment mean; prefetched reg-direct gather ----
__global__ __launch_bounds__(1024, 4) void agg_kernel(
    const float* __restrict__ grid_in, const unsigned short* __restrict__ f0b,
    const int* __restrict__ nbr_index, const int* __restrict__ offsets,
    const int* __restrict__ counts,
    const float* __restrict__ W0g, const float* __restrict__ b0g,
    const float* __restrict__ W1g, const float* __restrict__ b1g,
    const float* __restrict__ W2g, const float* __restrict__ b2g,
    unsigned short* __restrict__ f1b)
{
    __shared__ __attribute__((aligned(16))) unsigned short Tb[NWAVES * 16 * TPCH];
    __shared__ __attribute__((aligned(16))) unsigned short W0h[D1 * W0P], W0l[D1 * W0P];
    __shared__ __attribute__((aligned(16))) unsigned short W1h[D1 * W1P], W1l[D1 * W1P];
    __shared__ __attribute__((aligned(16))) float bs[192];
    __shared__ __attribute__((aligned(16))) float accH[VARS * PB * 33];
    __shared__ int offs[PB + 1];
    __shared__ int px2b[PB];
    __shared__ float invb[PB];

    const int t = threadIdx.x;
    const int lane = t & 63, wave = t >> 6;
    const int lm = lane & 15, quad = lane >> 4;
    const int p0 = blockIdx.x * PB;

    stage_split_weights(W0h, W0l, W1h, W1l, Tb, bs, W0g, b0g, W1g, b1g, W2g, b2g, t);
    if (t < PB) {
        offs[t] = offsets[p0 + t];
        int c = counts[p0 + t];
        invb[t] = 1.0f / (float)(c > 1 ? c : 1);
        float gx = grid_in[2 * (p0 + t)], gy = grid_in[2 * (p0 + t) + 1];
        px2b[t] = (int)(f2bf(gx) | ((unsigned int)f2bf(gy) << 16));
    }
    if (t == PB) offs[PB] = offsets[p0 + PB - 1] + counts[p0 + PB - 1];
    for (int idx = t; idx < VARS * PB * 33; idx += NT) accH[idx] = 0.0f;
    __syncthreads();

    bf16x8 w2f[12];
#pragma unroll
    for (int cb = 0; cb < 2; ++cb)
#pragma unroll
        for (int ks = 0; ks < 3; ++ks)
#pragma unroll
            for (int pl = 0; pl < 2; ++pl)
                w2f[(cb * 3 + ks) * 2 + pl] =
                    *(const bf16x8*)&Tb[pl * (OUTD * W1P) + (cb * 16 + lm) * W1P + ks * 32 + quad * 8];
    __syncthreads();
    // zero persistent pad [80..96) of this wave's 16 rows (never rewritten)
    unsigned short* TbW = Tb + (wave * 16) * TPCH;
    if (lane < 32)
        *(int4*)(TbW + (lane >> 1) * TPCH + 80 + (lane & 1) * 8) = make_int4(0, 0, 0, 0);

    const int e0 = offs[0];
    const int cntT = offs[PB] - e0;
    const int Rb = VARS * cntT;
    const int nch = (Rb + 15) >> 4;

    unsigned short* Trow = TbW + lm * TPCH;

    // prefetch state for chunk ch
    int pkey; int4 pfeats, pposf;
    {
        int myrow = (wave << 4) + lm;
        pkey = -1; pfeats = make_int4(0,0,0,0); pposf = make_int4(0,0,0,0);
        if (myrow < Rb) {
            int myv = (myrow >= 2 * cntT) ? 2 : ((myrow >= cntT) ? 1 : 0);
            int e = e0 + myrow - myv * cntT;
            int myj = nbr_index[e];
            int lp = 0;
#pragma unroll
            for (int l = 1; l < PB; ++l) lp += (e >= offs[l]);
            pkey = myv * PB + lp;
            const unsigned short* rec = f0b + ((size_t)(myv << 13) + myj) * RP;
            pfeats = ((const int4*)rec)[quad];
            if (quad == 0) pposf = make_int4(*(const int*)(rec + 32), px2b[lp], 0, 0);
        }
    }

    for (int ch = wave; ch < nch; ch += NWAVES) {
        int ckey = pkey; int4 cfeats = pfeats, cposf = pposf;
        // issue next chunk's gather before the MLP (latency hides behind MFMA)
        int nc = ch + NWAVES;
        pkey = -1; pfeats = make_int4(0,0,0,0); pposf = make_int4(0,0,0,0);
        if (nc < nch) {
            int myrow = (nc << 4) + lm;
            if (myrow < Rb) {
                int myv = (myrow >= 2 * cntT) ? 2 : ((myrow >= cntT) ? 1 : 0);
                int e = e0 + myrow - myv * cntT;
                int myj = nbr_index[e];
                int lp = 0;
#pragma unroll
                for (int l = 1; l < PB; ++l) lp += (e >= offs[l]);
                pkey = myv * PB + lp;
                const unsigned short* rec = f0b + ((size_t)(myv << 13) + myj) * RP;
                pfeats = ((const int4*)rec)[quad];
                if (quad == 0) pposf = make_int4(*(const int*)(rec + 32), px2b[lp], 0, 0);
            }
        }
        if (ckey < 0) { cfeats = make_int4(0,0,0,0); cposf = make_int4(0,0,0,0); }
        mlp_chunk(cfeats, cposf, Trow, W0h, W0l, W1h, W1l, w2f, bs, lm, quad);
        // keyed reduction of this wave's 16 rows into block accumulator
        int col = lane & 31, eo = lane >> 5;
#pragma unroll 1
        for (int e2 = eo; e2 < 16; e2 += 2) {
            int k = __shfl(ckey, e2);
            if (k >= 0)
                atomicAdd(&accH[k * 33 + col], ((const float*)(TbW + e2 * TPCH))[col]);
        }
    }
    __syncthreads();
    for (int idx = t; idx < VARS * PB * OUTD; idx += NT) {
        int key = idx >> 5, c = idx & 31;
        int v = key >> 4, lp = key & 15;
        size_t rec = ((size_t)(v << 13) + p0 + lp) * RP;
        float val = accH[key * 33 + c] * invb[lp] + bf2f(f0b[rec + c]);
        f1b[rec + c] = f2bf(val);
    }
    if (t < VARS * PB) {
        int v = t >> 4, lp = t & 15;
        *(int*)(f1b + ((size_t)(v << 13) + p0 + lp) * RP + 32) = px2b[lp];
    }
}

// ---- kNN MLP + mean over K ----
__global__ __launch_bounds__(1024, 4) void last_kernel(
    const unsigned short* __restrict__ f1b, const float* __restrict__ grid_out,
    const int* __restrict__ nbr_last,
    const float* __restrict__ W0g, const float* __restrict__ b0g,
    const float* __restrict__ W1g, const float* __restrict__ b1g,
    const float* __restrict__ W2g, const float* __restrict__ b2g,
    float* __restrict__ out)
{
    __shared__ __attribute__((aligned(16))) unsigned short Tb[NWAVES * 16 * TPCH];
    __shared__ __attribute__((aligned(16))) unsigned short W0h[D1 * W0P], W0l[D1 * W0P];
    __shared__ __attribute__((aligned(16))) unsigned short W1h[D1 * W1P], W1l[D1 * W1P];
    __shared__ __attribute__((aligned(16))) float bs[192];
    __shared__ __attribute__((aligned(16))) float accH[LPTS * VARS * 33];
    __shared__ int pxo2b[LPTS];

    const int t = threadIdx.x;
    const int lane = t & 63, wave = t >> 6;
    const int lm = lane & 15, quad = lane >> 4;
    const int m0 = blockIdx.x * LPTS;

    stage_split_weights(W0h, W0l, W1h, W1l, Tb, bs, W0g, b0g, W1g, b1g, W2g, b2g, t);
    if (t < LPTS) {
        float gx = grid_out[2 * (m0 + t)], gy = grid_out[2 * (m0 + t) + 1];
        pxo2b[t] = (int)(f2bf(gx) | ((unsigned int)f2bf(gy) << 16));
    }
    for (int idx = t; idx < LPTS * VARS * 33; idx += NT) accH[idx] = 0.0f;
    __syncthreads();

    bf16x8 w2f[12];
#pragma unroll
    for (int cb = 0; cb < 2; ++cb)
#pragma unroll
        for (int ks = 0; ks < 3; ++ks)
#pragma unroll
            for (int pl = 0; pl < 2; ++pl)
                w2f[(cb * 3 + ks) * 2 + pl] =
                    *(const bf16x8*)&Tb[pl * (OUTD * W1P) + (cb * 16 + lm) * W1P + ks * 32 + quad * 8];
    __syncthreads();
    unsigned short* TbW = Tb + (wave * 16) * TPCH;
    if (lane < 32)
        *(int4*)(TbW + (lane >> 1) * TPCH + 80 + (lane & 1) * 8) = make_int4(0, 0, 0, 0);

    const int Rb = LPTS * VARS * KLAST;   // 240
    const int nch = (Rb + 15) >> 4;       // 15
    unsigned short* Trow = TbW + lm * TPCH;

    for (int ch = wave; ch < nch; ch += NWAVES) {
        int myrow = (ch << 4) + lm;
        int ckey = -1; int4 cfeats = make_int4(0,0,0,0), cposf = make_int4(0,0,0,0);
        if (myrow < Rb) {
            int lp = myrow / 30, rr = myrow - lp * 30;
            int v = rr / KLAST, kk = rr - v * KLAST;
            int myj = nbr_last[(m0 + lp) * KLAST + kk];
            ckey = lp * VARS + v;
            const unsigned short* rec = f1b + ((size_t)(v << 13) + myj) * RP;
            cfeats = ((const int4*)rec)[quad];
            if (quad == 0) cposf = make_int4(*(const int*)(rec + 32), pxo2b[lp], 0, 0);
        }
        mlp_chunk(cfeats, cposf, Trow, W0h, W0l, W1h, W1l, w2f, bs, lm, quad);
        int col = lane & 31, eo = lane >> 5;
#pragma unroll 1
        for (int e2 = eo; e2 < 16; e2 += 2) {
            int k = __shfl(ckey, e2);
            if (k >= 0)
                atomicAdd(&accH[k * 33 + col], ((const float*)(TbW + e2 * TPCH))[col]);
        }
    }
    __syncthreads();
    if (t < LPTS * VARS * OUTD) {
        int key = t >> 5, c = t & 31;
        int lp = key / VARS, v = key - lp * VARS;
        out[((size_t)(m0 + lp) * VARS + v) * OUTD + c] = accH[key * 33 + c] * (1.0f / KLAST);
    }
}

extern "C" void kernel_launch(void* const* d_in, const int* in_sizes, int n_in,
                              void* d_out, int out_size, void* d_ws, size_t ws_size,
                              hipStream_t stream) {
    const float* inp      = (const float*)d_in[0];
    const float* grid_in  = (const float*)d_in[1];
    const float* grid_out = (const float*)d_in[2];
    const float* pW0 = (const float*)d_in[3];
    const float* pb0 = (const float*)d_in[4];
    const float* pW1 = (const float*)d_in[5];
    const float* pb1 = (const float*)d_in[6];
    const float* i0W0 = (const float*)d_in[7];
    const float* i0b0 = (const float*)d_in[8];
    const float* i0W1 = (const float*)d_in[9];
    const float* i0b1 = (const float*)d_in[10];
    const float* i0W2 = (const float*)d_in[11];
    const float* i0b2 = (const float*)d_in[12];
    const float* i1W0 = (const float*)d_in[13];
    const float* i1b0 = (const float*)d_in[14];
    const float* i1W1 = (const float*)d_in[15];
    const float* i1b1 = (const float*)d_in[16];
    const float* i1W2 = (const float*)d_in[17];
    const float* i1b2 = (const float*)d_in[18];
    const int* nbr_index  = (const int*)d_in[19];
    const int* nbr_counts = (const int*)d_in[21];
    const int* nbr_last   = (const int*)d_in[22];

    unsigned short* f0b = (unsigned short*)d_ws;                      // 3*8192*40 bf16
    unsigned short* f1b = f0b + (size_t)VARS * N_PTS * RP;            // 3*8192*40 bf16
    int* offsets = (int*)(f1b + (size_t)VARS * N_PTS * RP);           // N

    proj_kernel<<<(N_PTS * VARS) / 32, 256, 0, stream>>>(inp, grid_in, pW0, pb0, pW1, pb1, f0b);
    scan_kernel<<<1, 1024, 0, stream>>>(nbr_counts, offsets);
    agg_kernel<<<N_PTS / PB, NT, 0, stream>>>(grid_in, f0b, nbr_index, offsets, nbr_counts,
                                              i0W0, i0b0, i0W1, i0b1, i0W2, i0b2, f1b);
    last_kernel<<<M_PTS / LPTS, NT, 0, stream>>>(f1b, grid_out, nbr_last,
                                                 i1W0, i1b0, i1W1, i1b1, i1W2, i1b2,
                                                 (float*)d_out);
}

// Round 8
// 363.824 us; speedup vs baseline: 31.8971x; 1.0490x over previous
//
#include <hip/hip_runtime.h>
#include <math.h>

#define N_PTS 8192
#define M_PTS 2048
#define KLAST 10
#define VARS 3
#define OUTD 32
#define D1 80
#define D2 80
#define PB 16         // points per agg block (16 waves, 1024 threads)
#define LPTS 8        // output points per last block
#define NT 1024
#define NWAVES 16
#define TPCH 104      // Tb row pitch in bf16 (208 B)
#define W0P 72        // W0 K-pitch (K=64: feats 0..32, pos 32..36, pad ..64)
#define W1P 104       // W1/W2 K-pitch (K=80 padded to 96)
#define RP 40         // f0b/f1b record pitch in bf16 (80 B: [32 feats | ypos | pad])

typedef float f4 __attribute__((ext_vector_type(4)));
typedef short bf16x8 __attribute__((ext_vector_type(8)));

// tanh-approx gelu (max |err| ~3e-4; abs threshold 1.21e-2). Branch-free.
__device__ __forceinline__ float gelu_f(float x) {
    float x2 = x * x;
    float t = x * (0.7978845608028654f + 0.0356774081f * x2);
    float u = __expf(2.0f * t);
    float th = 1.0f - 2.0f * __builtin_amdgcn_rcpf(u + 1.0f);
    return 0.5f * x * (1.0f + th);
}
__device__ __forceinline__ unsigned short f2bf(float x) {
    unsigned int u = __float_as_uint(x);
    u += 0x7FFF + ((u >> 16) & 1);
    return (unsigned short)(u >> 16);
}
__device__ __forceinline__ float bf2f(unsigned short h) {
    return __uint_as_float(((unsigned int)h) << 16);
}

// Stage split (hi+lo bf16) weights transposed [col][k], K zero-padded.
// W0 k-order REORDERED to match record layout: k 0..31 <- W0g rows 4..35
// (features), k 32..35 <- W0g rows 0..3 (pos), k 36..63 <- 0.
// ALL weights live in LDS (w2f VGPR preload removed: with launch_bounds
// (1024,4)'s 128-reg cap it forced per-iteration scratch spills -> 100 MB
// WRITE/dispatch in R6/R7).
__device__ __forceinline__ void stage_split_weights(
    unsigned short* W0h, unsigned short* W0l,
    unsigned short* W1h, unsigned short* W1l,
    unsigned short* W2h, unsigned short* W2l, float* bs,
    const float* __restrict__ W0g, const float* __restrict__ b0g,
    const float* __restrict__ W1g, const float* __restrict__ b1g,
    const float* __restrict__ W2g, const float* __restrict__ b2g, int t)
{
    for (int idx = t; idx < D1 * W0P; idx += NT) {
        int col = idx / W0P, k = idx - col * W0P;
        float w = (k < 32) ? W0g[(k + 4) * D1 + col]
                           : ((k < 36) ? W0g[(k - 32) * D1 + col] : 0.0f);
        unsigned short h = f2bf(w);
        W0h[idx] = h; W0l[idx] = f2bf(w - bf2f(h));
    }
    for (int idx = t; idx < D1 * W1P; idx += NT) {
        int col = idx / W1P, k = idx - col * W1P;
        float w = (k < D2) ? W1g[k * D1 + col] : 0.0f;
        unsigned short h = f2bf(w);
        W1h[idx] = h; W1l[idx] = f2bf(w - bf2f(h));
    }
    for (int idx = t; idx < OUTD * W1P; idx += NT) {
        int col = idx / W1P, k = idx - col * W1P;
        float w = (k < D2) ? W2g[k * OUTD + col] : 0.0f;
        unsigned short h = f2bf(w);
        W2h[idx] = h; W2l[idx] = f2bf(w - bf2f(h));
    }
    for (int idx = t; idx < 192; idx += NT)
        bs[idx] = (idx < 80) ? b0g[idx] : (idx < 160 ? b1g[idx - 80] : b2g[idx - 160]);
}

// Per-wave 16-row chunk MLP. L1 B-operands arrive IN REGISTERS; H1/H2
// relayout via wave-private LDS rows (no barriers; same-wave DS ordering).
// Out = 32 floats at Trow[0..64) bf16 region. Pad [80..96) pre-zeroed once
// per wave. cb loops unroll-1 ON PURPOSE (full unroll -> scratch spills).
__device__ __forceinline__ void mlp_chunk(
    int4 featsi, int4 posfi, unsigned short* Trow,
    const unsigned short* W0h, const unsigned short* W0l,
    const unsigned short* W1h, const unsigned short* W1l,
    const unsigned short* W2h, const unsigned short* W2l,
    const float* bs, int lm, int quad)
{
    bf16x8 b1f0 = *(bf16x8*)&featsi;
    bf16x8 b1f1 = *(bf16x8*)&posfi;
    // ---- L1: K=64 (feats+pos+pad) -> 80, gelu ----
#pragma unroll 1
    for (int cb = 0; cb < 5; ++cb) {
        f4 acc = *(const f4*)&bs[cb * 16 + quad * 4];
        bf16x8 ah0 = *(const bf16x8*)&W0h[(cb * 16 + lm) * W0P + quad * 8];
        bf16x8 al0 = *(const bf16x8*)&W0l[(cb * 16 + lm) * W0P + quad * 8];
        bf16x8 ah1 = *(const bf16x8*)&W0h[(cb * 16 + lm) * W0P + 32 + quad * 8];
        bf16x8 al1 = *(const bf16x8*)&W0l[(cb * 16 + lm) * W0P + 32 + quad * 8];
        acc = __builtin_amdgcn_mfma_f32_16x16x32_bf16(ah0, b1f0, acc, 0, 0, 0);
        acc = __builtin_amdgcn_mfma_f32_16x16x32_bf16(al0, b1f0, acc, 0, 0, 0);
        acc = __builtin_amdgcn_mfma_f32_16x16x32_bf16(ah1, b1f1, acc, 0, 0, 0);
        acc = __builtin_amdgcn_mfma_f32_16x16x32_bf16(al1, b1f1, acc, 0, 0, 0);
        unsigned int pa = f2bf(gelu_f(acc.x)) | ((unsigned int)f2bf(gelu_f(acc.y)) << 16);
        unsigned int pb = f2bf(gelu_f(acc.z)) | ((unsigned int)f2bf(gelu_f(acc.w)) << 16);
        *(int2*)&Trow[cb * 16 + quad * 4] = make_int2((int)pa, (int)pb);
    }
    // ---- L2: 80(pad 96) -> 80, gelu ----
    bf16x8 b2f[3];
    b2f[0] = *(const bf16x8*)&Trow[quad * 8];
    b2f[1] = *(const bf16x8*)&Trow[32 + quad * 8];
    b2f[2] = *(const bf16x8*)&Trow[64 + quad * 8];
#pragma unroll 1
    for (int cb = 0; cb < 5; ++cb) {
        f4 acc = *(const f4*)&bs[80 + cb * 16 + quad * 4];
#pragma unroll
        for (int ks = 0; ks < 3; ++ks) {
            bf16x8 ah = *(const bf16x8*)&W1h[(cb * 16 + lm) * W1P + ks * 32 + quad * 8];
            bf16x8 al = *(const bf16x8*)&W1l[(cb * 16 + lm) * W1P + ks * 32 + quad * 8];
            acc = __builtin_amdgcn_mfma_f32_16x16x32_bf16(ah, b2f[ks], acc, 0, 0, 0);
            acc = __builtin_amdgcn_mfma_f32_16x16x32_bf16(al, b2f[ks], acc, 0, 0, 0);
        }
        unsigned int pa = f2bf(gelu_f(acc.x)) | ((unsigned int)f2bf(gelu_f(acc.y)) << 16);
        unsigned int pb = f2bf(gelu_f(acc.z)) | ((unsigned int)f2bf(gelu_f(acc.w)) << 16);
        *(int2*)&Trow[cb * 16 + quad * 4] = make_int2((int)pa, (int)pb);
    }
    // ---- L3: 80(pad 96) -> 32, fp32 out at Trow floats [0..32) ----
    bf16x8 b3f[3];
    b3f[0] = *(const bf16x8*)&Trow[quad * 8];
    b3f[1] = *(const bf16x8*)&Trow[32 + quad * 8];
    b3f[2] = *(const bf16x8*)&Trow[64 + quad * 8];
    float* po = (float*)Trow;
#pragma unroll 1
    for (int cb = 0; cb < 2; ++cb) {
        f4 acc = *(const f4*)&bs[160 + cb * 16 + quad * 4];
#pragma unroll
        for (int ks = 0; ks < 3; ++ks) {
            bf16x8 ah = *(const bf16x8*)&W2h[(cb * 16 + lm) * W1P + ks * 32 + quad * 8];
            bf16x8 al = *(const bf16x8*)&W2l[(cb * 16 + lm) * W1P + ks * 32 + quad * 8];
            acc = __builtin_amdgcn_mfma_f32_16x16x32_bf16(ah, b3f[ks], acc, 0, 0, 0);
            acc = __builtin_amdgcn_mfma_f32_16x16x32_bf16(al, b3f[ks], acc, 0, 0, 0);
        }
        *(f4*)&po[cb * 16 + quad * 4] = acc;
    }
}

// ---- fast exclusive scan ----
__global__ __launch_bounds__(1024) void scan_kernel(
    const int* __restrict__ counts, int* __restrict__ offsets)
{
    __shared__ int wtot[16], wexc[16];
    const int t = threadIdx.x, lane = t & 63, wave = t >> 6;
    int4 a = ((const int4*)counts)[2 * t];
    int4 b = ((const int4*)counts)[2 * t + 1];
    int e1 = a.x, e2 = e1 + a.y, e3 = e2 + a.z, e4 = e3 + a.w;
    int e5 = e4 + b.x, e6 = e5 + b.y, e7 = e6 + b.z;
    int s = e7 + b.w;
    int x = s;
#pragma unroll
    for (int d = 1; d < 64; d <<= 1) {
        int y = __shfl_up(x, d);
        if (lane >= d) x += y;
    }
    if (lane == 63) wtot[wave] = x;
    int lane_base = x - s;
    __syncthreads();
    if (wave == 0 && lane < 16) {
        int v = wtot[lane];
        int xx = v;
#pragma unroll
        for (int d = 1; d < 16; d <<= 1) {
            int y = __shfl_up(xx, d);
            if (lane >= d) xx += y;
        }
        wexc[lane] = xx - v;
    }
    __syncthreads();
    int base = wexc[wave] + lane_base;
    ((int4*)offsets)[2 * t]     = make_int4(base, base + e1, base + e2, base + e3);
    ((int4*)offsets)[2 * t + 1] = make_int4(base + e4, base + e5, base + e6, base + e7);
}

// ---- projection -> bf16 records f0b[(v<<13)+n]: [32 feats | ypos] ----
__global__ __launch_bounds__(256) void proj_kernel(
    const float* __restrict__ inp, const float* __restrict__ grid_in,
    const float* __restrict__ W0, const float* __restrict__ b0,
    const float* __restrict__ W1, const float* __restrict__ b1,
    unsigned short* __restrict__ f0b)
{
    __shared__ float W0s[8 * 64];
    __shared__ float W1s[64 * OUTD];
    __shared__ float xs[32 * 8];
    __shared__ float H[32 * 64];
    const int t = threadIdx.x;
    const int r0 = blockIdx.x * 32;
    for (int idx = t; idx < 512; idx += 256) W0s[idx] = W0[idx];
    for (int idx = t; idx < 64 * OUTD; idx += 256) W1s[idx] = W1[idx];
    xs[t] = inp[r0 * 8 + t];
    if (t < 32) {
        int row = r0 + t, n = row / 3, v = row - n * 3;
        float gx = grid_in[2 * n], gy = grid_in[2 * n + 1];
        unsigned int pk = f2bf(gx) | ((unsigned int)f2bf(gy) << 16);
        *(int*)(f0b + ((size_t)(v << 13) + n) * RP + 32) = (int)pk;
    }
    __syncthreads();
#pragma unroll 1
    for (int p = 0; p < 8; ++p) {
        int o = t + 256 * p, r = o >> 6, col = o & 63;
        float s = b0[col];
#pragma unroll
        for (int k = 0; k < 8; ++k) s += xs[r * 8 + k] * W0s[k * 64 + col];
        H[o] = gelu_f(s);
    }
    __syncthreads();
#pragma unroll 1
    for (int p = 0; p < 4; ++p) {
        int o = t + 256 * p, r = o >> 5, c = o & 31;
        float s = b1[c];
#pragma unroll 8
        for (int k = 0; k < 64; ++k) s += H[r * 64 + k] * W1s[k * OUTD + c];
        int row = r0 + r;
        int n = row / 3, v = row - n * 3;
        f0b[((size_t)(v << 13) + n) * RP + c] = f2bf(s);
    }
}

// ---- edge MLP + owner-computes segment mean; prefetched reg-direct gather ----
__global__ __launch_bounds__(1024, 4) void agg_kernel(
    const float* __restrict__ grid_in, const unsigned short* __restrict__ f0b,
    const int* __restrict__ nbr_index, const int* __restrict__ offsets,
    const int* __restrict__ counts,
    const float* __restrict__ W0g, const float* __restrict__ b0g,
    const float* __restrict__ W1g, const float* __restrict__ b1g,
    const float* __restrict__ W2g, const float* __restrict__ b2g,
    unsigned short* __restrict__ f1b)
{
    __shared__ __attribute__((aligned(16))) unsigned short Tb[NWAVES * 16 * TPCH];
    __shared__ __attribute__((aligned(16))) unsigned short W0h[D1 * W0P], W0l[D1 * W0P];
    __shared__ __attribute__((aligned(16))) unsigned short W1h[D1 * W1P], W1l[D1 * W1P];
    __shared__ __attribute__((aligned(16))) unsigned short W2h[OUTD * W1P], W2l[OUTD * W1P];
    __shared__ __attribute__((aligned(16))) float bs[192];
    __shared__ __attribute__((aligned(16))) float accH[VARS * PB * 33];
    __shared__ int offs[PB + 1];
    __shared__ int px2b[PB];
    __shared__ float invb[PB];

    const int t = threadIdx.x;
    const int lane = t & 63, wave = t >> 6;
    const int lm = lane & 15, quad = lane >> 4;
    const int p0 = blockIdx.x * PB;

    stage_split_weights(W0h, W0l, W1h, W1l, W2h, W2l, bs,
                        W0g, b0g, W1g, b1g, W2g, b2g, t);
    if (t < PB) {
        offs[t] = offsets[p0 + t];
        int c = counts[p0 + t];
        invb[t] = 1.0f / (float)(c > 1 ? c : 1);
        float gx = grid_in[2 * (p0 + t)], gy = grid_in[2 * (p0 + t) + 1];
        px2b[t] = (int)(f2bf(gx) | ((unsigned int)f2bf(gy) << 16));
    }
    if (t == PB) offs[PB] = offsets[p0 + PB - 1] + counts[p0 + PB - 1];
    for (int idx = t; idx < VARS * PB * 33; idx += NT) accH[idx] = 0.0f;
    __syncthreads();

    // zero persistent pad [80..96) of this wave's 16 rows (never rewritten)
    unsigned short* TbW = Tb + (wave * 16) * TPCH;
    if (lane < 32)
        *(int4*)(TbW + (lane >> 1) * TPCH + 80 + (lane & 1) * 8) = make_int4(0, 0, 0, 0);

    const int e0 = offs[0];
    const int cntT = offs[PB] - e0;
    const int Rb = VARS * cntT;
    const int nch = (Rb + 15) >> 4;

    unsigned short* Trow = TbW + lm * TPCH;

    // prefetch state for chunk ch
    int pkey; int4 pfeats, pposf;
    {
        int myrow = (wave << 4) + lm;
        pkey = -1; pfeats = make_int4(0,0,0,0); pposf = make_int4(0,0,0,0);
        if (myrow < Rb) {
            int myv = (myrow >= 2 * cntT) ? 2 : ((myrow >= cntT) ? 1 : 0);
            int e = e0 + myrow - myv * cntT;
            int myj = nbr_index[e];
            int lp = 0;
#pragma unroll
            for (int l = 1; l < PB; ++l) lp += (e >= offs[l]);
            pkey = myv * PB + lp;
            const unsigned short* rec = f0b + ((size_t)(myv << 13) + myj) * RP;
            pfeats = ((const int4*)rec)[quad];
            if (quad == 0) pposf = make_int4(*(const int*)(rec + 32), px2b[lp], 0, 0);
        }
    }

    for (int ch = wave; ch < nch; ch += NWAVES) {
        int ckey = pkey; int4 cfeats = pfeats, cposf = pposf;
        // issue next chunk's gather before the MLP (latency hides behind MFMA)
        int nc = ch + NWAVES;
        pkey = -1; pfeats = make_int4(0,0,0,0); pposf = make_int4(0,0,0,0);
        if (nc < nch) {
            int myrow = (nc << 4) + lm;
            if (myrow < Rb) {
                int myv = (myrow >= 2 * cntT) ? 2 : ((myrow >= cntT) ? 1 : 0);
                int e = e0 + myrow - myv * cntT;
                int myj = nbr_index[e];
                int lp = 0;
#pragma unroll
                for (int l = 1; l < PB; ++l) lp += (e >= offs[l]);
                pkey = myv * PB + lp;
                const unsigned short* rec = f0b + ((size_t)(myv << 13) + myj) * RP;
                pfeats = ((const int4*)rec)[quad];
                if (quad == 0) pposf = make_int4(*(const int*)(rec + 32), px2b[lp], 0, 0);
            }
        }
        if (ckey < 0) { cfeats = make_int4(0,0,0,0); cposf = make_int4(0,0,0,0); }
        mlp_chunk(cfeats, cposf, Trow, W0h, W0l, W1h, W1l, W2h, W2l, bs, lm, quad);
        // keyed reduction of this wave's 16 rows into block accumulator
        int col = lane & 31, eo = lane >> 5;
#pragma unroll 1
        for (int e2 = eo; e2 < 16; e2 += 2) {
            int k = __shfl(ckey, e2);
            if (k >= 0)
                atomicAdd(&accH[k * 33 + col], ((const float*)(TbW + e2 * TPCH))[col]);
        }
    }
    __syncthreads();
    for (int idx = t; idx < VARS * PB * OUTD; idx += NT) {
        int key = idx >> 5, c = idx & 31;
        int v = key >> 4, lp = key & 15;
        size_t rec = ((size_t)(v << 13) + p0 + lp) * RP;
        float val = accH[key * 33 + c] * invb[lp] + bf2f(f0b[rec + c]);
        f1b[rec + c] = f2bf(val);
    }
    if (t < VARS * PB) {
        int v = t >> 4, lp = t & 15;
        *(int*)(f1b + ((size_t)(v << 13) + p0 + lp) * RP + 32) = px2b[lp];
    }
}

// ---- kNN MLP + mean over K ----
__global__ __launch_bounds__(1024, 4) void last_kernel(
    const unsigned short* __restrict__ f1b, const float* __restrict__ grid_out,
    const int* __restrict__ nbr_last,
    const float* __restrict__ W0g, const float* __restrict__ b0g,
    const float* __restrict__ W1g, const float* __restrict__ b1g,
    const float* __restrict__ W2g, const float* __restrict__ b2g,
    float* __restrict__ out)
{
    __shared__ __attribute__((aligned(16))) unsigned short Tb[NWAVES * 16 * TPCH];
    __shared__ __attribute__((aligned(16))) unsigned short W0h[D1 * W0P], W0l[D1 * W0P];
    __shared__ __attribute__((aligned(16))) unsigned short W1h[D1 * W1P], W1l[D1 * W1P];
    __shared__ __attribute__((aligned(16))) unsigned short W2h[OUTD * W1P], W2l[OUTD * W1P];
    __shared__ __attribute__((aligned(16))) float bs[192];
    __shared__ __attribute__((aligned(16))) float accH[LPTS * VARS * 33];
    __shared__ int pxo2b[LPTS];

    const int t = threadIdx.x;
    const int lane = t & 63, wave = t >> 6;
    const int lm = lane & 15, quad = lane >> 4;
    const int m0 = blockIdx.x * LPTS;

    stage_split_weights(W0h, W0l, W1h, W1l, W2h, W2l, bs,
                        W0g, b0g, W1g, b1g, W2g, b2g, t);
    if (t < LPTS) {
        float gx = grid_out[2 * (m0 + t)], gy = grid_out[2 * (m0 + t) + 1];
        pxo2b[t] = (int)(f2bf(gx) | ((unsigned int)f2bf(gy) << 16));
    }
    for (int idx = t; idx < LPTS * VARS * 33; idx += NT) accH[idx] = 0.0f;
    __syncthreads();
    unsigned short* TbW = Tb + (wave * 16) * TPCH;
    if (lane < 32)
        *(int4*)(TbW + (lane >> 1) * TPCH + 80 + (lane & 1) * 8) = make_int4(0, 0, 0, 0);

    const int Rb = LPTS * VARS * KLAST;   // 240
    const int nch = (Rb + 15) >> 4;       // 15
    unsigned short* Trow = TbW + lm * TPCH;

    for (int ch = wave; ch < nch; ch += NWAVES) {
        int myrow = (ch << 4) + lm;
        int ckey = -1; int4 cfeats = make_int4(0,0,0,0), cposf = make_int4(0,0,0,0);
        if (myrow < Rb) {
            int lp = myrow / 30, rr = myrow - lp * 30;
            int v = rr / KLAST, kk = rr - v * KLAST;
            int myj = nbr_last[(m0 + lp) * KLAST + kk];
            ckey = lp * VARS + v;
            const unsigned short* rec = f1b + ((size_t)(v << 13) + myj) * RP;
            cfeats = ((const int4*)rec)[quad];
            if (quad == 0) cposf = make_int4(*(const int*)(rec + 32), pxo2b[lp], 0, 0);
        }
        mlp_chunk(cfeats, cposf, Trow, W0h, W0l, W1h, W1l, W2h, W2l, bs, lm, quad);
        int col = lane & 31, eo = lane >> 5;
#pragma unroll 1
        for (int e2 = eo; e2 < 16; e2 += 2) {
            int k = __shfl(ckey, e2);
            if (k >= 0)
                atomicAdd(&accH[k * 33 + col], ((const float*)(TbW + e2 * TPCH))[col]);
        }
    }
    __syncthreads();
    if (t < LPTS * VARS * OUTD) {
        int key = t >> 5, c = t & 31;
        int lp = key / VARS, v = key - lp * VARS;
        out[((size_t)(m0 + lp) * VARS + v) * OUTD + c] = accH[key * 33 + c] * (1.0f / KLAST);
    }
}

extern "C" void kernel_launch(void* const* d_in, const int* in_sizes, int n_in,
                              void* d_out, int out_size, void* d_ws, size_t ws_size,
                              hipStream_t stream) {
    const float* inp      = (const float*)d_in[0];
    const float* grid_in  = (const float*)d_in[1];
    const float* grid_out = (const float*)d_in[2];
    const float* pW0 = (const float*)d_in[3];
    const float* pb0 = (const float*)d_in[4];
    const float* pW1 = (const float*)d_in[5];
    const float* pb1 = (const float*)d_in[6];
    const float* i0W0 = (const float*)d_in[7];
    const float* i0b0 = (const float*)d_in[8];
    const float* i0W1 = (const float*)d_in[9];
    const float* i0b1 = (const float*)d_in[10];
    const float* i0W2 = (const float*)d_in[11];
    const float* i0b2 = (const float*)d_in[12];
    const float* i1W0 = (const float*)d_in[13];
    const float* i1b0 = (const float*)d_in[14];
    const float* i1W1 = (const float*)d_in[15];
    const float* i1b1 = (const float*)d_in[16];
    const float* i1W2 = (const float*)d_in[17];
    const float* i1b2 = (const float*)d_in[18];
    const int* nbr_index  = (const int*)d_in[19];
    const int* nbr_counts = (const int*)d_in[21];
    const int* nbr_last   = (const int*)d_in[22];

    unsigned short* f0b = (unsigned short*)d_ws;                      // 3*8192*40 bf16
    unsigned short* f1b = f0b + (size_t)VARS * N_PTS * RP;            // 3*8192*40 bf16
    int* offsets = (int*)(f1b + (size_t)VARS * N_PTS * RP);           // N

    proj_kernel<<<(N_PTS * VARS) / 32, 256, 0, stream>>>(inp, grid_in, pW0, pb0, pW1, pb1, f0b);
    scan_kernel<<<1, 1024, 0, stream>>>(nbr_counts, offsets);
    agg_kernel<<<N_PTS / PB, NT, 0, stream>>>(grid_in, f0b, nbr_index, offsets, nbr_counts,
                                              i0W0, i0b0, i0W1, i0b1, i0W2, i0b2, f1b);
    last_kernel<<<M_PTS / LPTS, NT, 0, stream>>>(f1b, grid_out, nbr_last,
                                                 i1W0, i1b0, i1W1, i1b1, i1W2, i1b2,
                                                 (float*)d_out);
}